// Round 1
// baseline (32177.658 us; speedup 1.0000x reference)
//
#include <hip/hip_runtime.h>
#include <math.h>

static constexpr int TT = 16384;
static constexpr int DD = 1024;
static constexpr int FF = 2048;
static constexpr int VV = 4096;

// ---------------------------------------------------------------------------
// SGEMM: O[M,N] = epi(A[M,K] @ B[K,N]) ; EPI 0=store, 1=relu, 2=residual(+X)
// 128x128 tile, BK=16, 256 threads, 8x8 per thread (2x2 groups of 4x4).
// As stored transposed [16][132] (pad 4 -> conflict-free transpose writes and
// broadcast reads). Bs [16][128], row-contiguous. Register prefetch of next
// tile overlaps global loads with FMA work.
// ---------------------------------------------------------------------------
template<int EPI, bool ROWLIM>
__global__ __launch_bounds__(256, 2)
void sgemm_kernel(const float* __restrict__ A, const float* __restrict__ B,
                  const float* __restrict__ X, float* __restrict__ O,
                  int M, int N, int K, const int* __restrict__ rowlim)
{
    const int m0 = blockIdx.y * 128;
    const int n0 = blockIdx.x * 128;
    if constexpr (ROWLIM) {
        if (m0 >= *rowlim) return;   // rows >= kept-count are unused
    }

    __shared__ float As[16][132];
    __shared__ float Bs[16][128];

    const int tid  = threadIdx.x;
    const int tx   = tid & 15;        // 0..15  (column group)
    const int ty   = tid >> 4;        // 0..15  (row group)
    const int arow = tid >> 2;        // 0..63  (A tile row, +64 for 2nd half)
    const int akq  = tid & 3;         // k-quad within BK=16
    const int brow = tid >> 5;        // 0..7   (B tile row, +8 for 2nd half)
    const int bcq  = tid & 31;        // column quad

    const float* Ab = A + (size_t)(m0 + arow) * K + akq * 4;
    const float* Bb = B + (size_t)brow * N + n0 + bcq * 4;

    float4 pa0, pa1, pb0, pb1;
    pa0 = *(const float4*)(Ab);
    pa1 = *(const float4*)(Ab + (size_t)64 * K);
    pb0 = *(const float4*)(Bb);
    pb1 = *(const float4*)(Bb + (size_t)8 * N);

    float acc[8][8];
    #pragma unroll
    for (int i = 0; i < 8; ++i)
        #pragma unroll
        for (int j = 0; j < 8; ++j) acc[i][j] = 0.f;

    // store tile 0
    As[akq*4+0][arow]    = pa0.x; As[akq*4+1][arow]    = pa0.y;
    As[akq*4+2][arow]    = pa0.z; As[akq*4+3][arow]    = pa0.w;
    As[akq*4+0][arow+64] = pa1.x; As[akq*4+1][arow+64] = pa1.y;
    As[akq*4+2][arow+64] = pa1.z; As[akq*4+3][arow+64] = pa1.w;
    *(float4*)&Bs[brow][bcq*4]     = pb0;
    *(float4*)&Bs[brow + 8][bcq*4] = pb1;
    __syncthreads();

    const int nt = K >> 4;
    for (int t = 0; t < nt; ++t) {
        if (t + 1 < nt) {   // prefetch next tile into registers
            const float* Ap = Ab + (t + 1) * 16;
            pa0 = *(const float4*)(Ap);
            pa1 = *(const float4*)(Ap + (size_t)64 * K);
            const float* Bp = Bb + (size_t)(t + 1) * 16 * N;
            pb0 = *(const float4*)(Bp);
            pb1 = *(const float4*)(Bp + (size_t)8 * N);
        }
        #pragma unroll
        for (int k = 0; k < 16; ++k) {
            float a[8], b[8];
            *(float4*)&a[0] = *(const float4*)&As[k][ty * 4];
            *(float4*)&a[4] = *(const float4*)&As[k][64 + ty * 4];
            *(float4*)&b[0] = *(const float4*)&Bs[k][tx * 4];
            *(float4*)&b[4] = *(const float4*)&Bs[k][64 + tx * 4];
            #pragma unroll
            for (int i = 0; i < 8; ++i)
                #pragma unroll
                for (int j = 0; j < 8; ++j)
                    acc[i][j] = fmaf(a[i], b[j], acc[i][j]);
        }
        if (t + 1 < nt) {
            __syncthreads();
            As[akq*4+0][arow]    = pa0.x; As[akq*4+1][arow]    = pa0.y;
            As[akq*4+2][arow]    = pa0.z; As[akq*4+3][arow]    = pa0.w;
            As[akq*4+0][arow+64] = pa1.x; As[akq*4+1][arow+64] = pa1.y;
            As[akq*4+2][arow+64] = pa1.z; As[akq*4+3][arow+64] = pa1.w;
            *(float4*)&Bs[brow][bcq*4]     = pb0;
            *(float4*)&Bs[brow + 8][bcq*4] = pb1;
            __syncthreads();
        }
    }

    // epilogue
    #pragma unroll
    for (int i = 0; i < 8; ++i) {
        const int r = m0 + ((i >> 2) ? 64 : 0) + ty * 4 + (i & 3);
        #pragma unroll
        for (int jc = 0; jc < 2; ++jc) {
            const int c = n0 + jc * 64 + tx * 4;
            float4 v = make_float4(acc[i][jc*4+0], acc[i][jc*4+1],
                                   acc[i][jc*4+2], acc[i][jc*4+3]);
            if constexpr (EPI == 1) {
                v.x = fmaxf(v.x, 0.f); v.y = fmaxf(v.y, 0.f);
                v.z = fmaxf(v.z, 0.f); v.w = fmaxf(v.w, 0.f);
            } else if constexpr (EPI == 2) {
                float4 xv = *(const float4*)(X + (size_t)r * N + c);
                v.x += xv.x; v.y += xv.y; v.z += xv.z; v.w += xv.w;
            }
            *(float4*)(O + (size_t)r * N + c) = v;
        }
    }
}

// ---------------------------------------------------------------------------
// Gate: w[t] = sigmoid(enc[t]·sp_w + sp_b); mask = w >= 0.5 (sigmoid computed
// so the exact-0.5 rounding near logit 0 matches the reference semantics).
// One wave per token.
// ---------------------------------------------------------------------------
__global__ void gate_kernel(const float* __restrict__ enc,
                            const float* __restrict__ spw,
                            const float* __restrict__ spb,
                            float* __restrict__ w, int* __restrict__ mi)
{
    const int t    = blockIdx.x * 4 + (threadIdx.x >> 6);
    const int lane = threadIdx.x & 63;
    float s = 0.f;
    const float* row = enc + (size_t)t * DD;
    for (int k = lane; k < DD; k += 64) s += row[k] * spw[k];
    #pragma unroll
    for (int off = 32; off > 0; off >>= 1) s += __shfl_xor(s, off, 64);
    if (lane == 0) {
        const float logit = s + spb[0];
        const float sg = 1.f / (1.f + expf(-logit));
        w[t]  = sg;
        mi[t] = (sg >= 0.5f) ? 1 : 0;
    }
}

// ---------------------------------------------------------------------------
// Scan: exclusive cumsum of mask over T (single block, 256 threads x 64 tok),
// meta[0]=total kept K, meta[1+s]=ecs[cu[s]] (kept-count before segment s).
// ---------------------------------------------------------------------------
__global__ void scan_kernel(const int* __restrict__ mi, const int* __restrict__ cu,
                            int* __restrict__ ecs, int* __restrict__ meta)
{
    __shared__ int sums[256];
    const int tid  = threadIdx.x;
    const int base = tid * 64;
    int s = 0;
    for (int i = 0; i < 64; ++i) s += mi[base + i];
    sums[tid] = s;
    __syncthreads();
    for (int off = 1; off < 256; off <<= 1) {
        int v = (tid >= off) ? sums[tid - off] : 0;
        __syncthreads();
        sums[tid] += v;
        __syncthreads();
    }
    int run = (tid == 0) ? 0 : sums[tid - 1];
    for (int i = 0; i < 64; ++i) { ecs[base + i] = run; run += mi[base + i]; }
    if (tid == 255) meta[0] = sums[255];
    if (tid < 4) {
        const int idx = cu[tid];          // segment starts
        const int tc = idx >> 6, rem = idx & 63;
        int e = (tc == 0) ? 0 : sums[tc - 1];
        for (int i = 0; i < rem; ++i) e += mi[tc * 64 + i];
        meta[1 + tid] = e;
    }
}

// ---------------------------------------------------------------------------
// Pack: for kept token t -> P[ecs[t]] = enc[t]*w[t] + pos_emb[ecs[t]-base[seg]]
// (P pre-zeroed; dropped tokens write nothing). One wave per token.
// ---------------------------------------------------------------------------
__global__ void pack_kernel(const float* __restrict__ enc, const float* __restrict__ w,
                            const int* __restrict__ mi, const int* __restrict__ ecs,
                            const int* __restrict__ cu, const int* __restrict__ meta,
                            const float* __restrict__ pos_emb, float* __restrict__ P)
{
    const int t    = blockIdx.x * 4 + (threadIdx.x >> 6);
    const int lane = threadIdx.x & 63;
    if (!mi[t]) return;                       // wave-uniform
    const int e = ecs[t];
    int seg = 0;
    #pragma unroll
    for (int ss = 1; ss < 4; ++ss) if (t >= cu[ss]) seg = ss;
    const int np = e - meta[1 + seg];
    const float wt = w[t];
    const float4* src = (const float4*)(enc + (size_t)t * DD);
    const float4* pe  = (const float4*)(pos_emb + (size_t)np * DD);
    float4* dst = (float4*)(P + (size_t)e * DD);
    for (int c = lane; c < DD / 4; c += 64) {
        float4 v = src[c], p = pe[c];
        v.x = v.x * wt + p.x; v.y = v.y * wt + p.y;
        v.z = v.z * wt + p.z; v.w = v.w * wt + p.w;
        dst[c] = v;
    }
}

// ---------------------------------------------------------------------------
// Combine: C[t] = mask[t] ? bb[ecs[t]] : enc[t]. One wave per token.
// ---------------------------------------------------------------------------
__global__ void combine_kernel(const float* __restrict__ enc, const float* __restrict__ P,
                               const int* __restrict__ mi, const int* __restrict__ ecs,
                               float* __restrict__ C)
{
    const int t    = blockIdx.x * 4 + (threadIdx.x >> 6);
    const int lane = threadIdx.x & 63;
    const float4* src = mi[t] ? (const float4*)(P + (size_t)ecs[t] * DD)
                              : (const float4*)(enc + (size_t)t * DD);
    float4* dst = (float4*)(C + (size_t)t * DD);
    for (int c = lane; c < DD / 4; c += 64) dst[c] = src[c];
}

// ---------------------------------------------------------------------------
extern "C" void kernel_launch(void* const* d_in, const int* in_sizes, int n_in,
                              void* d_out, int out_size, void* d_ws, size_t ws_size,
                              hipStream_t stream)
{
    (void)in_sizes; (void)n_in; (void)out_size; (void)ws_size;
    const float* x   = (const float*)d_in[0];
    const float* ew1 = (const float*)d_in[1];
    const float* ew2 = (const float*)d_in[2];
    const float* bw1 = (const float*)d_in[3];
    const float* bw2 = (const float*)d_in[4];
    const float* dw1 = (const float*)d_in[5];
    const float* dw2 = (const float*)d_in[6];
    const float* spw = (const float*)d_in[7];
    const float* spb = (const float*)d_in[8];
    const float* pem = (const float*)d_in[9];
    const float* lmh = (const float*)d_in[10];
    const int*   cu  = (const int*)d_in[11];
    float* out = (float*)d_out;

    // workspace layout (~336 MB)
    float* ws  = (float*)d_ws;
    float* H   = ws;                              // [T,F]
    float* ENC = H   + (size_t)TT * FF;           // [T,D]
    float* P   = ENC + (size_t)TT * DD;           // [T,D] gathered -> bb (in place)
    float* C   = P   + (size_t)TT * DD;           // [T,D] combined -> dec (in place)
    float* WG  = C   + (size_t)TT * DD;           // [T] gate values
    int*   MI   = (int*)(WG + TT);                // [T] keep mask
    int*   ECS  = MI + TT;                        // [T] exclusive cumsum
    int*   META = ECS + TT;                       // [8] K, base[4]

    const dim3 blk(256);
    const dim3 gF(FF / 128, TT / 128);
    const dim3 gD(DD / 128, TT / 128);
    const dim3 gV(VV / 128, TT / 128);

    // encoder MLP (fp32 — gate-critical path)
    sgemm_kernel<1, false><<<gF, blk, 0, stream>>>(x, ew1, nullptr, H, TT, FF, DD, nullptr);
    sgemm_kernel<2, false><<<gD, blk, 0, stream>>>(H, ew2, x, ENC, TT, DD, FF, nullptr);

    // gate + ragged repack bookkeeping
    gate_kernel<<<TT / 4, blk, 0, stream>>>(ENC, spw, spb, WG, MI);
    scan_kernel<<<1, blk, 0, stream>>>(MI, cu, ECS, META);
    hipMemsetAsync(P, 0, (size_t)TT * DD * sizeof(float), stream);
    pack_kernel<<<TT / 4, blk, 0, stream>>>(ENC, WG, MI, ECS, cu, META, pem, P);

    // backbone MLP on packed rows only (row-limit early exit; in-place residual)
    sgemm_kernel<1, true><<<gF, blk, 0, stream>>>(P, bw1, nullptr, H, TT, FF, DD, META);
    sgemm_kernel<2, true><<<gD, blk, 0, stream>>>(H, bw2, P, P, TT, DD, FF, META);

    // scatter-combine
    combine_kernel<<<TT / 4, blk, 0, stream>>>(ENC, P, MI, ECS, C);

    // decoder MLP (in-place residual on C)
    sgemm_kernel<1, false><<<gF, blk, 0, stream>>>(C, dw1, nullptr, H, TT, FF, DD, nullptr);
    sgemm_kernel<2, false><<<gD, blk, 0, stream>>>(H, dw2, C, C, TT, DD, FF, nullptr);

    // lm head
    sgemm_kernel<0, false><<<gV, blk, 0, stream>>>(C, lmh, nullptr, out, TT, VV, DD, nullptr);
}

// Round 2
// 960.214 us; speedup vs baseline: 33.5109x; 33.5109x over previous
//
#include <hip/hip_runtime.h>
#include <hip/hip_bf16.h>
#include <math.h>

static constexpr int TT = 16384;
static constexpr int DD = 1024;
static constexpr int FF = 2048;
static constexpr int VV = 4096;

using bf16 = __hip_bfloat16;
typedef __attribute__((ext_vector_type(8))) short bf16x8;
typedef __attribute__((ext_vector_type(4))) float f32x4;

__device__ inline void gload16(const void* g, void* l) {
    __builtin_amdgcn_global_load_lds(
        (const __attribute__((address_space(1))) void*)g,
        (__attribute__((address_space(3))) void*)l, 16, 0, 0);
}

// ---------------------------------------------------------------------------
// MFMA GEMM: O = epi(A @ B), A [M,K] bf16 row-major, BT [N,K] bf16 (B^T).
// 128x128 tile, BK=32, 4 waves (2x2), 4x4 frags of 16x16x32 per wave.
// NT3: 3-term hi/lo split (A={Ah,Al}, B={Bh,Bl}), acc += AhBh + AhBl + AlBh.
// GPART: per-row partial dots  sum_c relu(O[r][c]) * qv[c]  -> gpart slots.
// ---------------------------------------------------------------------------
template<bool NT3, bool RELU, bool RESID, bool WB16, bool WF32, bool GPART, bool ROWLIM>
__global__ __launch_bounds__(256, 2)
void mgemm(const bf16* __restrict__ Ah, const bf16* __restrict__ Al,
           const bf16* __restrict__ Bh, const bf16* __restrict__ Bl,
           const float* __restrict__ X, bf16* __restrict__ Ob,
           float* __restrict__ Of, float* __restrict__ gpart,
           const float* __restrict__ qv,
           int M, int N, int K, const int* __restrict__ rowlim)
{
    if constexpr (ROWLIM) { if ((int)blockIdx.y * 128 >= *rowlim) return; }
    const int m0 = blockIdx.y * 128, n0 = blockIdx.x * 128;

    extern __shared__ char smem[];
    bf16* sAh = (bf16*)smem;                 // [128][32]
    bf16* sBh = (bf16*)(smem + 8192);        // [128][32]
    bf16* sAl = (bf16*)(smem + 16384);
    bf16* sBl = (bf16*)(smem + 24576);

    const int tid = threadIdx.x;
    const int wv = tid >> 6, ln = tid & 63;
    const int wm = wv >> 1, wn = wv & 1;
    const int lr = ln & 15, lk = ln >> 4;
    const int arow = ln >> 2;            // 0..15
    const int acol = (ln & 3) * 8;       // 0,8,16,24

    const bf16* Abase_h = Ah + (size_t)m0 * K;
    const bf16* Abase_l = NT3 ? (Al + (size_t)m0 * K) : nullptr;
    const bf16* Bbase_h = Bh + (size_t)n0 * K;
    const bf16* Bbase_l = NT3 ? (Bl + (size_t)n0 * K) : nullptr;

    f32x4 acc[4][4];
    #pragma unroll
    for (int m = 0; m < 4; ++m)
        #pragma unroll
        for (int n = 0; n < 4; ++n) acc[m][n] = (f32x4){0.f, 0.f, 0.f, 0.f};

    const int nt = K >> 5;
    for (int kt = 0; kt < nt; ++kt) {
        // stage: LDS dest is wave-uniform base; HW scatters lane*16B (linear)
        #pragma unroll
        for (int p = 0; p < 2; ++p) {
            const int row = p * 64 + wv * 16;
            gload16(Abase_h + (size_t)(row + arow) * K + kt * 32 + acol, sAh + row * 32);
            gload16(Bbase_h + (size_t)(row + arow) * K + kt * 32 + acol, sBh + row * 32);
            if constexpr (NT3) {
                gload16(Abase_l + (size_t)(row + arow) * K + kt * 32 + acol, sAl + row * 32);
                gload16(Bbase_l + (size_t)(row + arow) * K + kt * 32 + acol, sBl + row * 32);
            }
        }
        __syncthreads();

        bf16x8 ah[4], bh[4];
        #pragma unroll
        for (int m = 0; m < 4; ++m)
            ah[m] = *(const bf16x8*)(sAh + (wm * 64 + m * 16 + lr) * 32 + lk * 8);
        #pragma unroll
        for (int n = 0; n < 4; ++n)
            bh[n] = *(const bf16x8*)(sBh + (wn * 64 + n * 16 + lr) * 32 + lk * 8);

        if constexpr (NT3) {
            bf16x8 al[4], bl[4];
            #pragma unroll
            for (int m = 0; m < 4; ++m)
                al[m] = *(const bf16x8*)(sAl + (wm * 64 + m * 16 + lr) * 32 + lk * 8);
            #pragma unroll
            for (int n = 0; n < 4; ++n)
                bl[n] = *(const bf16x8*)(sBl + (wn * 64 + n * 16 + lr) * 32 + lk * 8);
            #pragma unroll
            for (int m = 0; m < 4; ++m)
                #pragma unroll
                for (int n = 0; n < 4; ++n) {
                    acc[m][n] = __builtin_amdgcn_mfma_f32_16x16x32_bf16(ah[m], bh[n], acc[m][n], 0, 0, 0);
                    acc[m][n] = __builtin_amdgcn_mfma_f32_16x16x32_bf16(ah[m], bl[n], acc[m][n], 0, 0, 0);
                    acc[m][n] = __builtin_amdgcn_mfma_f32_16x16x32_bf16(al[m], bh[n], acc[m][n], 0, 0, 0);
                }
        } else {
            #pragma unroll
            for (int m = 0; m < 4; ++m)
                #pragma unroll
                for (int n = 0; n < 4; ++n)
                    acc[m][n] = __builtin_amdgcn_mfma_f32_16x16x32_bf16(ah[m], bh[n], acc[m][n], 0, 0, 0);
        }
        __syncthreads();
    }

    if constexpr (GPART) {
        float qvv[4];
        #pragma unroll
        for (int n = 0; n < 4; ++n) qvv[n] = qv[n0 + wn * 64 + n * 16 + lr];
        #pragma unroll
        for (int m = 0; m < 4; ++m)
            #pragma unroll
            for (int r = 0; r < 4; ++r) {
                float s = 0.f;
                #pragma unroll
                for (int n = 0; n < 4; ++n) s += fmaxf(acc[m][n][r], 0.f) * qvv[n];
                s += __shfl_xor(s, 1, 64); s += __shfl_xor(s, 2, 64);
                s += __shfl_xor(s, 4, 64); s += __shfl_xor(s, 8, 64);
                if (lr == 0)
                    gpart[(size_t)(blockIdx.x * 2 + wn) * M + (m0 + wm * 64 + m * 16 + lk * 4 + r)] = s;
            }
    }

    #pragma unroll
    for (int m = 0; m < 4; ++m)
        #pragma unroll
        for (int n = 0; n < 4; ++n)
            #pragma unroll
            for (int r = 0; r < 4; ++r) {
                const int row = m0 + wm * 64 + m * 16 + lk * 4 + r;
                const int col = n0 + wn * 64 + n * 16 + lr;
                float v = acc[m][n][r];
                if constexpr (RELU)  v = fmaxf(v, 0.f);
                if constexpr (RESID) v += X[(size_t)row * N + col];
                if constexpr (WF32)  Of[(size_t)row * N + col] = v;
                if constexpr (WB16)  Ob[(size_t)row * N + col] = __float2bfloat16(v);
            }
}

// ---------------------------------------------------------------------------
// Weight transpose+cast: W [R][C] fp32 -> T [C][R] bf16 (optional hi/lo split)
// ---------------------------------------------------------------------------
template<bool SPLIT>
__global__ void wtrans(const float* __restrict__ W, bf16* __restrict__ Th,
                       bf16* __restrict__ Tl, int R, int C)
{
    __shared__ float tile[32][33];
    const int tx = threadIdx.x & 31, ty = threadIdx.x >> 5;  // 32x8
    const int rb = blockIdx.y * 32, cb = blockIdx.x * 32;
    #pragma unroll
    for (int i = 0; i < 32; i += 8)
        tile[ty + i][tx] = W[(size_t)(rb + ty + i) * C + cb + tx];
    __syncthreads();
    #pragma unroll
    for (int i = 0; i < 32; i += 8) {
        const float v = tile[tx][ty + i];
        const size_t o = (size_t)(cb + ty + i) * R + rb + tx;
        const bf16 h = __float2bfloat16(v);
        Th[o] = h;
        if constexpr (SPLIT) Tl[o] = __float2bfloat16(v - __bfloat162float(h));
    }
}

// x fp32 -> hi/lo bf16 split
__global__ void splitx(const float* __restrict__ x, bf16* __restrict__ xh,
                       bf16* __restrict__ xl)
{
    const int i = blockIdx.x * 256 + threadIdx.x;
    const float4 v = ((const float4*)x)[i];
    const float f[4] = {v.x, v.y, v.z, v.w};
    #pragma unroll
    for (int j = 0; j < 4; ++j) {
        const bf16 h = __float2bfloat16(f[j]);
        xh[i * 4 + j] = h;
        xl[i * 4 + j] = __float2bfloat16(f[j] - __bfloat162float(h));
    }
}

// q[f] = sum_d w2[f][d] * sp[d]
__global__ void qvec(const float* __restrict__ w2, const float* __restrict__ sp,
                     float* __restrict__ q)
{
    const int f  = blockIdx.x * 4 + (threadIdx.x >> 6);
    const int ln = threadIdx.x & 63;
    float s = 0.f;
    const float* row = w2 + (size_t)f * DD;
    for (int k = ln; k < DD; k += 64) s += row[k] * sp[k];
    #pragma unroll
    for (int off = 32; off > 0; off >>= 1) s += __shfl_xor(s, off, 64);
    if (ln == 0) q[f] = s;
}

// gate logit[t] = x[t]·sp + sum_slots gpart[slot][t] + spb ; w, mask
__global__ void gate2(const float* __restrict__ x, const float* __restrict__ spw,
                      const float* __restrict__ spb, const float* __restrict__ gpart,
                      float* __restrict__ w, int* __restrict__ mi)
{
    const int t  = blockIdx.x * 4 + (threadIdx.x >> 6);
    const int ln = threadIdx.x & 63;
    float s = 0.f;
    const float* row = x + (size_t)t * DD;
    for (int k = ln; k < DD; k += 64) s += row[k] * spw[k];
    if (ln < 32) s += gpart[(size_t)ln * TT + t];
    #pragma unroll
    for (int off = 32; off > 0; off >>= 1) s += __shfl_xor(s, off, 64);
    if (ln == 0) {
        const float sg = 1.f / (1.f + expf(-(s + spb[0])));
        w[t]  = sg;
        mi[t] = (sg >= 0.5f) ? 1 : 0;
    }
}

// exclusive cumsum of mask + per-segment bases
__global__ void scan_kernel(const int* __restrict__ mi, const int* __restrict__ cu,
                            int* __restrict__ ecs, int* __restrict__ meta)
{
    __shared__ int sums[256];
    const int tid  = threadIdx.x;
    const int base = tid * 64;
    int s = 0;
    for (int i = 0; i < 64; ++i) s += mi[base + i];
    sums[tid] = s;
    __syncthreads();
    for (int off = 1; off < 256; off <<= 1) {
        int v = (tid >= off) ? sums[tid - off] : 0;
        __syncthreads();
        sums[tid] += v;
        __syncthreads();
    }
    int run = (tid == 0) ? 0 : sums[tid - 1];
    for (int i = 0; i < 64; ++i) { ecs[base + i] = run; run += mi[base + i]; }
    if (tid == 255) meta[0] = sums[255];
    if (tid < 4) {
        const int idx = cu[tid];
        const int tc = idx >> 6, rem = idx & 63;
        int e = (tc == 0) ? 0 : sums[tc - 1];
        for (int i = 0; i < rem; ++i) e += mi[tc * 64 + i];
        meta[1 + tid] = e;
    }
}

// pack kept rows: Pf[e] = enc[t]*w[t] + pos_emb[rank], Pb = bf16(Pf)
__global__ void pack_kernel(const float* __restrict__ enc, const float* __restrict__ w,
                            const int* __restrict__ mi, const int* __restrict__ ecs,
                            const int* __restrict__ cu, const int* __restrict__ meta,
                            const float* __restrict__ pos_emb,
                            float* __restrict__ Pf, bf16* __restrict__ Pb)
{
    const int t    = blockIdx.x * 4 + (threadIdx.x >> 6);
    const int lane = threadIdx.x & 63;
    if (!mi[t]) return;
    const int e = ecs[t];
    int seg = 0;
    #pragma unroll
    for (int ss = 1; ss < 4; ++ss) if (t >= cu[ss]) seg = ss;
    const int np = e - meta[1 + seg];
    const float wt = w[t];
    const float4* src = (const float4*)(enc + (size_t)t * DD);
    const float4* pe  = (const float4*)(pos_emb + (size_t)np * DD);
    float4* dstf = (float4*)(Pf + (size_t)e * DD);
    bf16*   dstb = Pb + (size_t)e * DD;
    for (int c = lane; c < DD / 4; c += 64) {
        float4 v = src[c], p = pe[c];
        v.x = v.x * wt + p.x; v.y = v.y * wt + p.y;
        v.z = v.z * wt + p.z; v.w = v.w * wt + p.w;
        dstf[c] = v;
        dstb[c * 4 + 0] = __float2bfloat16(v.x);
        dstb[c * 4 + 1] = __float2bfloat16(v.y);
        dstb[c * 4 + 2] = __float2bfloat16(v.z);
        dstb[c * 4 + 3] = __float2bfloat16(v.w);
    }
}

// combine: kept -> Cf(=ENC in place) = BBf[ecs], all rows -> Cb = bf16(Cf)
__global__ void combine_kernel(float* __restrict__ ENC, const float* __restrict__ BBf,
                               const int* __restrict__ mi, const int* __restrict__ ecs,
                               bf16* __restrict__ Cb)
{
    const int t    = blockIdx.x * 4 + (threadIdx.x >> 6);
    const int lane = threadIdx.x & 63;
    const bool kept = mi[t] != 0;
    const float4* src = kept ? (const float4*)(BBf + (size_t)ecs[t] * DD)
                             : (const float4*)(ENC + (size_t)t * DD);
    float4* dstf = (float4*)(ENC + (size_t)t * DD);
    bf16*   dstb = Cb + (size_t)t * DD;
    for (int c = lane; c < DD / 4; c += 64) {
        const float4 v = src[c];
        if (kept) dstf[c] = v;
        dstb[c * 4 + 0] = __float2bfloat16(v.x);
        dstb[c * 4 + 1] = __float2bfloat16(v.y);
        dstb[c * 4 + 2] = __float2bfloat16(v.z);
        dstb[c * 4 + 3] = __float2bfloat16(v.w);
    }
}

// ---------------------------------------------------------------------------
extern "C" void kernel_launch(void* const* d_in, const int* in_sizes, int n_in,
                              void* d_out, int out_size, void* d_ws, size_t ws_size,
                              hipStream_t stream)
{
    (void)in_sizes; (void)n_in; (void)out_size; (void)ws_size;
    const float* x   = (const float*)d_in[0];
    const float* ew1 = (const float*)d_in[1];
    const float* ew2 = (const float*)d_in[2];
    const float* bw1 = (const float*)d_in[3];
    const float* bw2 = (const float*)d_in[4];
    const float* dw1 = (const float*)d_in[5];
    const float* dw2 = (const float*)d_in[6];
    const float* spw = (const float*)d_in[7];
    const float* spb = (const float*)d_in[8];
    const float* pem = (const float*)d_in[9];
    const float* lmh = (const float*)d_in[10];
    const int*   cu  = (const int*)d_in[11];
    float* out = (float*)d_out;

    // ---- workspace carve (~329 MB; round 1 proved >= 335 MB usable) ----
    char* w = (char*)d_ws;
    auto alloc = [&](size_t bytes) { char* p = w; w += bytes; return p; };
    bf16* ew1hT = (bf16*)alloc((size_t)FF * DD * 2);
    bf16* ew1lT = (bf16*)alloc((size_t)FF * DD * 2);
    bf16* ew2T  = (bf16*)alloc((size_t)DD * FF * 2);
    bf16* bw1T  = (bf16*)alloc((size_t)FF * DD * 2);
    bf16* bw2T  = (bf16*)alloc((size_t)DD * FF * 2);
    bf16* lmhT  = (bf16*)alloc((size_t)VV * DD * 2);
    float* qv   = (float*)alloc((size_t)FF * 4);
    float* GP   = (float*)alloc((size_t)32 * TT * 4);
    float* WG   = (float*)alloc((size_t)TT * 4);
    int*   MI   = (int*)alloc((size_t)TT * 4);
    int*   ECS  = (int*)alloc((size_t)TT * 4);
    int*   META = (int*)alloc(64);
    bf16* Xh    = (bf16*)alloc((size_t)TT * DD * 2);   // later: DECb
    bf16* Xl    = (bf16*)alloc((size_t)TT * DD * 2);   // later: Cb
    bf16* Hb    = (bf16*)alloc((size_t)TT * FF * 2);   // hidden (all MLPs)
    float* ENC  = (float*)alloc((size_t)TT * DD * 4);  // later: Cf (in place)
    float* Pf   = (float*)alloc((size_t)TT * DD * 4);  // later: BBf (in place)
    bf16* Pb    = (bf16*)alloc((size_t)TT * DD * 2);
    bf16* dw1T  = ew1hT;   // alias: encoder split weights dead after GEMM1
    bf16* dw2T  = ew1lT;

    const dim3 blk(256);

    // ---- prep ----
    splitx<<<TT * DD / 4 / 256, blk, 0, stream>>>(x, Xh, Xl);
    wtrans<true ><<<dim3(FF / 32, DD / 32), blk, 0, stream>>>(ew1, ew1hT, ew1lT, DD, FF);
    wtrans<false><<<dim3(DD / 32, FF / 32), blk, 0, stream>>>(ew2, ew2T, nullptr, FF, DD);
    wtrans<false><<<dim3(FF / 32, DD / 32), blk, 0, stream>>>(bw1, bw1T, nullptr, DD, FF);
    wtrans<false><<<dim3(DD / 32, FF / 32), blk, 0, stream>>>(bw2, bw2T, nullptr, FF, DD);
    wtrans<false><<<dim3(VV / 32, DD / 32), blk, 0, stream>>>(lmh, lmhT, nullptr, DD, VV);
    qvec<<<FF / 4, blk, 0, stream>>>(ew2, spw, qv);

    // ---- encoder GEMM1 (3-term split, relu, bf16 out, gate partials) ----
    mgemm<true, true, false, true, false, true, false>
        <<<dim3(FF / 128, TT / 128), blk, 32768, stream>>>(
        Xh, Xl, ew1hT, ew1lT, nullptr, Hb, nullptr, GP, qv, TT, FF, DD, nullptr);

    // ---- gate + scan ----
    gate2<<<TT / 4, blk, 0, stream>>>(x, spw, spb, GP, WG, MI);
    scan_kernel<<<1, blk, 0, stream>>>(MI, cu, ECS, META);

    // ---- encoder GEMM2: ENC = Hb @ ew2 + x (fp32 out) ----
    mgemm<false, false, true, false, true, false, false>
        <<<dim3(DD / 128, TT / 128), blk, 16384, stream>>>(
        Hb, nullptr, ew2T, nullptr, x, nullptr, ENC, nullptr, nullptr, TT, DD, FF, nullptr);

    // ---- pack kept rows ----
    pack_kernel<<<TT / 4, blk, 0, stream>>>(ENC, WG, MI, ECS, cu, META, pem, Pf, Pb);

    // decoder weight transposes (into encoder-weight alias; after GEMM1)
    wtrans<false><<<dim3(FF / 32, DD / 32), blk, 0, stream>>>(dw1, dw1T, nullptr, DD, FF);
    wtrans<false><<<dim3(DD / 32, FF / 32), blk, 0, stream>>>(dw2, dw2T, nullptr, FF, DD);

    // ---- backbone (rowlim) ----
    mgemm<false, true, false, true, false, false, true>
        <<<dim3(FF / 128, TT / 128), blk, 16384, stream>>>(
        Pb, nullptr, bw1T, nullptr, nullptr, Hb, nullptr, nullptr, nullptr, TT, FF, DD, META);
    mgemm<false, false, true, false, true, false, true>
        <<<dim3(DD / 128, TT / 128), blk, 16384, stream>>>(
        Hb, nullptr, bw2T, nullptr, Pf, nullptr, Pf, nullptr, nullptr, TT, DD, FF, META);

    // ---- scatter-combine (Cf = ENC in place, Cb bf16) ----
    combine_kernel<<<TT / 4, blk, 0, stream>>>(ENC, Pf, MI, ECS, Xl);

    // ---- decoder ----
    mgemm<false, true, false, true, false, false, false>
        <<<dim3(FF / 128, TT / 128), blk, 16384, stream>>>(
        Xl, nullptr, dw1T, nullptr, nullptr, Hb, nullptr, nullptr, nullptr, TT, FF, DD, nullptr);
    mgemm<false, false, true, true, false, false, false>
        <<<dim3(DD / 128, TT / 128), blk, 16384, stream>>>(
        Hb, nullptr, dw2T, nullptr, ENC, Xh, nullptr, nullptr, nullptr, TT, DD, FF, nullptr);

    // ---- lm head ----
    mgemm<false, false, false, false, true, false, false>
        <<<dim3(VV / 128, TT / 128), blk, 16384, stream>>>(
        Xh, nullptr, lmhT, nullptr, nullptr, nullptr, out, nullptr, nullptr, TT, VV, DD, nullptr);
}

// Round 4
// 864.487 us; speedup vs baseline: 37.2217x; 1.1107x over previous
//
#include <hip/hip_runtime.h>
#include <hip/hip_bf16.h>
#include <math.h>

static constexpr int TT = 16384;
static constexpr int DD = 1024;
static constexpr int FF = 2048;
static constexpr int VV = 4096;

using bf16 = __hip_bfloat16;
typedef __attribute__((ext_vector_type(8))) short bf16x8;
typedef __attribute__((ext_vector_type(4))) float f32x4;

__device__ inline void gload16(const void* g, void* l) {
    __builtin_amdgcn_global_load_lds(
        (const __attribute__((address_space(1))) void*)g,
        (__attribute__((address_space(3))) void*)l, 16, 0, 0);
}

// ===========================================================================
// 8-phase 256x256 MFMA GEMM (m201 template, corrected stage stream).
// A [M,K] bf16 row-major, BT [N,K] bf16 (B^T). 512 thr = 8 waves (2M x 4N),
// per-wave out 128x64 (8 mf x 4 nf frags of 16x16x32). BK=64, 2 K-tiles/iter.
// LDS 128 KiB: buf{0,1} x {A[256][64] | B[256][64]}.
// Stage stream: half j (j>=0) staged sequentially; tile=j>>2, part=j&3 with
// part order {B h0, B h1, A h0, A h1} -> B region (read only at group phase 0)
// is restaged first; A halves land in phases where A reads are done/ending.
// vmcnt(6)=3 halves at phases A3/B3 -> tile t+1 / t+2 landed exactly in time.
// ===========================================================================
template<int EPI /*0 none,1 relu,2 +X*/, bool WB16, bool WF32, bool ROWLIM>
__global__ __launch_bounds__(512, 2)
void mgemm8(const bf16* __restrict__ A, const bf16* __restrict__ BT,
            const float* __restrict__ X, bf16* __restrict__ Ob,
            float* __restrict__ Of,
            int M, int N, int K, const int* __restrict__ rowlim)
{
    if constexpr (ROWLIM) { if ((int)blockIdx.y * 256 >= *rowlim) return; }
    const int m0 = blockIdx.y * 256, n0 = blockIdx.x * 256;

    extern __shared__ char smem[];   // 2 bufs x (A 32K | B 32K) = 128 KiB

    const int tid = threadIdx.x;
    const int wv = tid >> 6, ln = tid & 63;
    const int wm = wv >> 2, wn = wv & 3;       // wave tile: rows wm*128, cols wn*64
    const int lr = ln & 15, lk = ln >> 4;
    const int swz = (lr & 7) << 4;

    const bf16* Ag = A  + (size_t)m0 * K;
    const bf16* Bg = BT + (size_t)n0 * K;

    const int NT = K >> 6;        // 64-wide K-tiles (even, >= 4)
    const int NI = NT >> 1;

    // frag-read lds offsets
    const int aoff0 = (wm * 128 + lr) * 128;
    const int boff0 = 32768 + (wn * 64 + lr) * 128;
    const int cb0 = (lk * 16) ^ swz;
    const int cb1 = (64 + lk * 16) ^ swz;

    // stage one half-tile (128 rows x 64 cols): 2 x global_load_lds per wave.
    // LDS dest linear; global source column pre-swizzled (same involution the
    // reads apply): lane ln -> r=ln>>3 (row), colgroup (ln&7)^r.
    auto STAGE = [&](const bf16* g, int h, int kt, int buf, int op) {
        const int r = ln >> 3;
        const int c = ((ln & 7) ^ r) * 8;
        const bf16* s = g + (size_t)(h * 128 + wv * 16 + r) * K + kt * 64 + c;
        char* d = smem + buf * 65536 + op * 32768 + h * 16384 + wv * 2048;
        gload16(s, d);
        gload16(s + (size_t)8 * K, d + 1024);
    };
    // stage half j of the sequential stream (guarded past the last tile)
    auto stage_j = [&](int j) {
        const int tile = j >> 2;
        if (tile >= NT) return;
        const int part = j & 3;
        const int buf = tile & 1;
        if (part < 2) STAGE(Bg, part, tile, buf, 1);
        else          STAGE(Ag, part - 2, tile, buf, 0);
    };

    bf16x8 afr[2][2], bfr[4][2];
    f32x4 acc[8][4];
    #pragma unroll
    for (int m = 0; m < 8; ++m)
        #pragma unroll
        for (int n = 0; n < 4; ++n) acc[m][n] = (f32x4){0.f, 0.f, 0.f, 0.f};

#define DS_A(BUF, Q) do {                                                     \
    const char* _p = smem + (BUF) * 65536 + aoff0 + (Q) * 4096;               \
    afr[0][0] = *(const bf16x8*)(_p + cb0);                                   \
    afr[0][1] = *(const bf16x8*)(_p + cb1);                                   \
    afr[1][0] = *(const bf16x8*)(_p + 2048 + cb0);                            \
    afr[1][1] = *(const bf16x8*)(_p + 2048 + cb1);                            \
} while (0)

#define DS_B(BUF) do {                                                        \
    const char* _p = smem + (BUF) * 65536 + boff0;                            \
    _Pragma("unroll")                                                         \
    for (int nf = 0; nf < 4; ++nf) {                                          \
        bfr[nf][0] = *(const bf16x8*)(_p + nf * 2048 + cb0);                  \
        bfr[nf][1] = *(const bf16x8*)(_p + nf * 2048 + cb1);                  \
    }                                                                         \
} while (0)

#define MFMAQ(Q) do {                                                         \
    __builtin_amdgcn_s_setprio(1);                                            \
    _Pragma("unroll")                                                         \
    for (int m2 = 0; m2 < 2; ++m2)                                            \
        _Pragma("unroll")                                                     \
        for (int nf = 0; nf < 4; ++nf) {                                      \
            acc[(Q) * 2 + m2][nf] = __builtin_amdgcn_mfma_f32_16x16x32_bf16(  \
                afr[m2][0], bfr[nf][0], acc[(Q) * 2 + m2][nf], 0, 0, 0);      \
            acc[(Q) * 2 + m2][nf] = __builtin_amdgcn_mfma_f32_16x16x32_bf16(  \
                afr[m2][1], bfr[nf][1], acc[(Q) * 2 + m2][nf], 0, 0, 0);      \
        }                                                                     \
    __builtin_amdgcn_s_setprio(0);                                            \
} while (0)

// W: 0 = no wait, 1 = vmcnt(6), 2 = vmcnt(0)
#define PHASE(Q, BUF, DOB, J, W)                                              \
    {                                                                         \
        DS_A(BUF, Q);                                                         \
        if (DOB) DS_B(BUF);                                                   \
        stage_j(J);                                                           \
        if ((W) == 1)      asm volatile("s_waitcnt vmcnt(6)" ::: "memory");   \
        else if ((W) == 2) asm volatile("s_waitcnt vmcnt(0)" ::: "memory");   \
        __builtin_amdgcn_sched_barrier(0);                                    \
        __builtin_amdgcn_s_barrier();                                         \
        MFMAQ(Q);                                                             \
        __builtin_amdgcn_s_barrier();                                         \
    }

    // prologue — halves 0..6: tile0 {Bh0,Bh1,Ah0,Ah1} -> buf0, vmcnt(4);
    // tile1 {Bh0,Bh1,Ah0} -> buf1, vmcnt(6) => tile0 fully landed; barrier.
    STAGE(Bg, 0, 0, 0, 1); STAGE(Bg, 1, 0, 0, 1);
    STAGE(Ag, 0, 0, 0, 0); STAGE(Ag, 1, 0, 0, 0);
    asm volatile("s_waitcnt vmcnt(4)" ::: "memory");
    STAGE(Bg, 0, 1, 1, 1); STAGE(Bg, 1, 1, 1, 1);
    STAGE(Ag, 0, 1, 1, 0);
    asm volatile("s_waitcnt vmcnt(6)" ::: "memory");
    __builtin_amdgcn_sched_barrier(0);
    __builtin_amdgcn_s_barrier();

    for (int i = 0; i < NI; ++i) {
        const int jb = 7 + 8 * i;
        const bool last = (i + 1 == NI);
        // group A: compute tile 2i from buf0
        PHASE(0, 0, true,  jb + 0, 0);
        PHASE(1, 0, false, jb + 1, 0);
        PHASE(2, 0, false, jb + 2, 0);
        PHASE(3, 0, false, jb + 3, last ? 2 : 1);
        // group B: compute tile 2i+1 from buf1
        PHASE(0, 1, true,  jb + 4, 0);
        PHASE(1, 1, false, jb + 5, 0);
        PHASE(2, 1, false, jb + 6, 0);
        PHASE(3, 1, false, jb + 7, last ? 0 : 1);
    }

#undef PHASE
#undef MFMAQ
#undef DS_B
#undef DS_A

    // epilogue: C[row = m0+wm*128+mf*16+lk*4+rr][col = n0+wn*64+nf*16+lr]
    #pragma unroll
    for (int mf = 0; mf < 8; ++mf)
        #pragma unroll
        for (int nf = 0; nf < 4; ++nf)
            #pragma unroll
            for (int rr = 0; rr < 4; ++rr) {
                const int row = m0 + wm * 128 + mf * 16 + lk * 4 + rr;
                const int col = n0 + wn * 64 + nf * 16 + lr;
                float v = acc[mf][nf][rr];
                if constexpr (EPI == 1) v = fmaxf(v, 0.f);
                if constexpr (EPI == 2) v += X[(size_t)row * N + col];
                if constexpr (WB16) Ob[(size_t)row * N + col] = __float2bfloat16(v);
                if constexpr (WF32) Of[(size_t)row * N + col] = v;
            }
}

// ---------------------------------------------------------------------------
// NT3 encoder GEMM1 (round-2 verified): 3-term hi/lo split, 128x128, BK=32,
// relu, bf16 out, fused gate partial dots.
// ---------------------------------------------------------------------------
__global__ __launch_bounds__(256, 2)
void mgemm_nt3(const bf16* __restrict__ Ah, const bf16* __restrict__ Al,
               const bf16* __restrict__ Bh, const bf16* __restrict__ Bl,
               bf16* __restrict__ Ob, float* __restrict__ gpart,
               const float* __restrict__ qv, int M, int N, int K)
{
    const int m0 = blockIdx.y * 128, n0 = blockIdx.x * 128;

    extern __shared__ char smem[];
    bf16* sAh = (bf16*)smem;
    bf16* sBh = (bf16*)(smem + 8192);
    bf16* sAl = (bf16*)(smem + 16384);
    bf16* sBl = (bf16*)(smem + 24576);

    const int tid = threadIdx.x;
    const int wv = tid >> 6, ln = tid & 63;
    const int wm = wv >> 1, wn = wv & 1;
    const int lr = ln & 15, lk = ln >> 4;
    const int arow = ln >> 2;
    const int acol = (ln & 3) * 8;

    const bf16* Abase_h = Ah + (size_t)m0 * K;
    const bf16* Abase_l = Al + (size_t)m0 * K;
    const bf16* Bbase_h = Bh + (size_t)n0 * K;
    const bf16* Bbase_l = Bl + (size_t)n0 * K;

    f32x4 acc[4][4];
    #pragma unroll
    for (int m = 0; m < 4; ++m)
        #pragma unroll
        for (int n = 0; n < 4; ++n) acc[m][n] = (f32x4){0.f, 0.f, 0.f, 0.f};

    const int nt = K >> 5;
    for (int kt = 0; kt < nt; ++kt) {
        #pragma unroll
        for (int p = 0; p < 2; ++p) {
            const int row = p * 64 + wv * 16;
            gload16(Abase_h + (size_t)(row + arow) * K + kt * 32 + acol, sAh + row * 32);
            gload16(Bbase_h + (size_t)(row + arow) * K + kt * 32 + acol, sBh + row * 32);
            gload16(Abase_l + (size_t)(row + arow) * K + kt * 32 + acol, sAl + row * 32);
            gload16(Bbase_l + (size_t)(row + arow) * K + kt * 32 + acol, sBl + row * 32);
        }
        __syncthreads();

        bf16x8 ah[4], bh[4], al[4], bl[4];
        #pragma unroll
        for (int m = 0; m < 4; ++m) {
            ah[m] = *(const bf16x8*)(sAh + (wm * 64 + m * 16 + lr) * 32 + lk * 8);
            al[m] = *(const bf16x8*)(sAl + (wm * 64 + m * 16 + lr) * 32 + lk * 8);
        }
        #pragma unroll
        for (int n = 0; n < 4; ++n) {
            bh[n] = *(const bf16x8*)(sBh + (wn * 64 + n * 16 + lr) * 32 + lk * 8);
            bl[n] = *(const bf16x8*)(sBl + (wn * 64 + n * 16 + lr) * 32 + lk * 8);
        }
        #pragma unroll
        for (int m = 0; m < 4; ++m)
            #pragma unroll
            for (int n = 0; n < 4; ++n) {
                acc[m][n] = __builtin_amdgcn_mfma_f32_16x16x32_bf16(ah[m], bh[n], acc[m][n], 0, 0, 0);
                acc[m][n] = __builtin_amdgcn_mfma_f32_16x16x32_bf16(ah[m], bl[n], acc[m][n], 0, 0, 0);
                acc[m][n] = __builtin_amdgcn_mfma_f32_16x16x32_bf16(al[m], bh[n], acc[m][n], 0, 0, 0);
            }
        __syncthreads();
    }

    {
        float qvv[4];
        #pragma unroll
        for (int n = 0; n < 4; ++n) qvv[n] = qv[n0 + wn * 64 + n * 16 + lr];
        #pragma unroll
        for (int m = 0; m < 4; ++m)
            #pragma unroll
            for (int r = 0; r < 4; ++r) {
                float s = 0.f;
                #pragma unroll
                for (int n = 0; n < 4; ++n) s += fmaxf(acc[m][n][r], 0.f) * qvv[n];
                s += __shfl_xor(s, 1, 64); s += __shfl_xor(s, 2, 64);
                s += __shfl_xor(s, 4, 64); s += __shfl_xor(s, 8, 64);
                if (lr == 0)
                    gpart[(size_t)(blockIdx.x * 2 + wn) * M + (m0 + wm * 64 + m * 16 + lk * 4 + r)] = s;
            }
    }

    #pragma unroll
    for (int m = 0; m < 4; ++m)
        #pragma unroll
        for (int n = 0; n < 4; ++n)
            #pragma unroll
            for (int r = 0; r < 4; ++r) {
                const int row = m0 + wm * 64 + m * 16 + lk * 4 + r;
                const int col = n0 + wn * 64 + n * 16 + lr;
                Ob[(size_t)row * N + col] = __float2bfloat16(fmaxf(acc[m][n][r], 0.f));
            }
}

// ---------------------------------------------------------------------------
template<bool SPLIT>
__global__ void wtrans(const float* __restrict__ W, bf16* __restrict__ Th,
                       bf16* __restrict__ Tl, int R, int C)
{
    __shared__ float tile[32][33];
    const int tx = threadIdx.x & 31, ty = threadIdx.x >> 5;
    const int rb = blockIdx.y * 32, cb = blockIdx.x * 32;
    #pragma unroll
    for (int i = 0; i < 32; i += 8)
        tile[ty + i][tx] = W[(size_t)(rb + ty + i) * C + cb + tx];
    __syncthreads();
    #pragma unroll
    for (int i = 0; i < 32; i += 8) {
        const float v = tile[tx][ty + i];
        const size_t o = (size_t)(cb + ty + i) * R + rb + tx;
        const bf16 h = __float2bfloat16(v);
        Th[o] = h;
        if constexpr (SPLIT) Tl[o] = __float2bfloat16(v - __bfloat162float(h));
    }
}

__global__ void splitx(const float* __restrict__ x, bf16* __restrict__ xh,
                       bf16* __restrict__ xl)
{
    const int i = blockIdx.x * 256 + threadIdx.x;
    const float4 v = ((const float4*)x)[i];
    const float f[4] = {v.x, v.y, v.z, v.w};
    #pragma unroll
    for (int j = 0; j < 4; ++j) {
        const bf16 h = __float2bfloat16(f[j]);
        xh[i * 4 + j] = h;
        xl[i * 4 + j] = __float2bfloat16(f[j] - __bfloat162float(h));
    }
}

__global__ void qvec(const float* __restrict__ w2, const float* __restrict__ sp,
                     float* __restrict__ q)
{
    const int f  = blockIdx.x * 4 + (threadIdx.x >> 6);
    const int ln = threadIdx.x & 63;
    float s = 0.f;
    const float* row = w2 + (size_t)f * DD;
    for (int k = ln; k < DD; k += 64) s += row[k] * sp[k];
    #pragma unroll
    for (int off = 32; off > 0; off >>= 1) s += __shfl_xor(s, off, 64);
    if (ln == 0) q[f] = s;
}

__global__ void gate2(const float* __restrict__ x, const float* __restrict__ spw,
                      const float* __restrict__ spb, const float* __restrict__ gpart,
                      float* __restrict__ w, int* __restrict__ mi)
{
    const int t  = blockIdx.x * 4 + (threadIdx.x >> 6);
    const int ln = threadIdx.x & 63;
    float s = 0.f;
    const float* row = x + (size_t)t * DD;
    for (int k = ln; k < DD; k += 64) s += row[k] * spw[k];
    if (ln < 32) s += gpart[(size_t)ln * TT + t];
    #pragma unroll
    for (int off = 32; off > 0; off >>= 1) s += __shfl_xor(s, off, 64);
    if (ln == 0) {
        const float sg = 1.f / (1.f + expf(-(s + spb[0])));
        w[t]  = sg;
        mi[t] = (sg >= 0.5f) ? 1 : 0;
    }
}

__global__ void scan_kernel(const int* __restrict__ mi, const int* __restrict__ cu,
                            int* __restrict__ ecs, int* __restrict__ meta)
{
    __shared__ int sums[256];
    const int tid  = threadIdx.x;
    const int base = tid * 64;
    int s = 0;
    for (int i = 0; i < 64; ++i) s += mi[base + i];
    sums[tid] = s;
    __syncthreads();
    for (int off = 1; off < 256; off <<= 1) {
        int v = (tid >= off) ? sums[tid - off] : 0;
        __syncthreads();
        sums[tid] += v;
        __syncthreads();
    }
    int run = (tid == 0) ? 0 : sums[tid - 1];
    for (int i = 0; i < 64; ++i) { ecs[base + i] = run; run += mi[base + i]; }
    if (tid == 255) meta[0] = sums[255];
    if (tid < 4) {
        const int idx = cu[tid];
        const int tc = idx >> 6, rem = idx & 63;
        int e = (tc == 0) ? 0 : sums[tc - 1];
        for (int i = 0; i < rem; ++i) e += mi[tc * 64 + i];
        meta[1 + tid] = e;
    }
}

__global__ void pack_kernel(const float* __restrict__ enc, const float* __restrict__ w,
                            const int* __restrict__ mi, const int* __restrict__ ecs,
                            const int* __restrict__ cu, const int* __restrict__ meta,
                            const float* __restrict__ pos_emb,
                            float* __restrict__ Pf, bf16* __restrict__ Pb)
{
    const int t    = blockIdx.x * 4 + (threadIdx.x >> 6);
    const int lane = threadIdx.x & 63;
    if (!mi[t]) return;
    const int e = ecs[t];
    int seg = 0;
    #pragma unroll
    for (int ss = 1; ss < 4; ++ss) if (t >= cu[ss]) seg = ss;
    const int np = e - meta[1 + seg];
    const float wt = w[t];
    const float4* src = (const float4*)(enc + (size_t)t * DD);
    const float4* pe  = (const float4*)(pos_emb + (size_t)np * DD);
    float4* dstf = (float4*)(Pf + (size_t)e * DD);
    bf16*   dstb = Pb + (size_t)e * DD;
    for (int c = lane; c < DD / 4; c += 64) {
        float4 v = src[c], p = pe[c];
        v.x = v.x * wt + p.x; v.y = v.y * wt + p.y;
        v.z = v.z * wt + p.z; v.w = v.w * wt + p.w;
        dstf[c] = v;
        dstb[c * 4 + 0] = __float2bfloat16(v.x);
        dstb[c * 4 + 1] = __float2bfloat16(v.y);
        dstb[c * 4 + 2] = __float2bfloat16(v.z);
        dstb[c * 4 + 3] = __float2bfloat16(v.w);
    }
}

__global__ void combine_kernel(float* __restrict__ ENC, const float* __restrict__ BBf,
                               const int* __restrict__ mi, const int* __restrict__ ecs,
                               bf16* __restrict__ Cb)
{
    const int t    = blockIdx.x * 4 + (threadIdx.x >> 6);
    const int lane = threadIdx.x & 63;
    const bool kept = mi[t] != 0;
    const float4* src = kept ? (const float4*)(BBf + (size_t)ecs[t] * DD)
                             : (const float4*)(ENC + (size_t)t * DD);
    float4* dstf = (float4*)(ENC + (size_t)t * DD);
    bf16*   dstb = Cb + (size_t)t * DD;
    for (int c = lane; c < DD / 4; c += 64) {
        const float4 v = src[c];
        if (kept) dstf[c] = v;
        dstb[c * 4 + 0] = __float2bfloat16(v.x);
        dstb[c * 4 + 1] = __float2bfloat16(v.y);
        dstb[c * 4 + 2] = __float2bfloat16(v.z);
        dstb[c * 4 + 3] = __float2bfloat16(v.w);
    }
}

// ---------------------------------------------------------------------------
extern "C" void kernel_launch(void* const* d_in, const int* in_sizes, int n_in,
                              void* d_out, int out_size, void* d_ws, size_t ws_size,
                              hipStream_t stream)
{
    (void)in_sizes; (void)n_in; (void)out_size; (void)ws_size;
    const float* x   = (const float*)d_in[0];
    const float* ew1 = (const float*)d_in[1];
    const float* ew2 = (const float*)d_in[2];
    const float* bw1 = (const float*)d_in[3];
    const float* bw2 = (const float*)d_in[4];
    const float* dw1 = (const float*)d_in[5];
    const float* dw2 = (const float*)d_in[6];
    const float* spw = (const float*)d_in[7];
    const float* spb = (const float*)d_in[8];
    const float* pem = (const float*)d_in[9];
    const float* lmh = (const float*)d_in[10];
    const int*   cu  = (const int*)d_in[11];
    float* out = (float*)d_out;

    // opt-in to 128 KiB dynamic LDS (idempotent)
    (void)hipFuncSetAttribute((const void*)mgemm8<2, false, true, false>,
                              hipFuncAttributeMaxDynamicSharedMemorySize, 131072);
    (void)hipFuncSetAttribute((const void*)mgemm8<1, true, false, true>,
                              hipFuncAttributeMaxDynamicSharedMemorySize, 131072);
    (void)hipFuncSetAttribute((const void*)mgemm8<2, false, true, true>,
                              hipFuncAttributeMaxDynamicSharedMemorySize, 131072);
    (void)hipFuncSetAttribute((const void*)mgemm8<1, true, false, false>,
                              hipFuncAttributeMaxDynamicSharedMemorySize, 131072);
    (void)hipFuncSetAttribute((const void*)mgemm8<2, true, false, false>,
                              hipFuncAttributeMaxDynamicSharedMemorySize, 131072);
    (void)hipFuncSetAttribute((const void*)mgemm8<0, false, true, false>,
                              hipFuncAttributeMaxDynamicSharedMemorySize, 131072);

    // ---- workspace carve (~329 MB) ----
    char* w = (char*)d_ws;
    auto alloc = [&](size_t bytes) { char* p = w; w += bytes; return p; };
    bf16* ew1hT = (bf16*)alloc((size_t)FF * DD * 2);
    bf16* ew1lT = (bf16*)alloc((size_t)FF * DD * 2);
    bf16* ew2T  = (bf16*)alloc((size_t)DD * FF * 2);
    bf16* bw1T  = (bf16*)alloc((size_t)FF * DD * 2);
    bf16* bw2T  = (bf16*)alloc((size_t)DD * FF * 2);
    bf16* lmhT  = (bf16*)alloc((size_t)VV * DD * 2);
    float* qv   = (float*)alloc((size_t)FF * 4);
    float* GP   = (float*)alloc((size_t)32 * TT * 4);
    float* WG   = (float*)alloc((size_t)TT * 4);
    int*   MI   = (int*)alloc((size_t)TT * 4);
    int*   ECS  = (int*)alloc((size_t)TT * 4);
    int*   META = (int*)alloc(64);
    bf16* Xh    = (bf16*)alloc((size_t)TT * DD * 2);   // later: DECb
    bf16* Xl    = (bf16*)alloc((size_t)TT * DD * 2);   // later: Cb
    bf16* Hb    = (bf16*)alloc((size_t)TT * FF * 2);   // hidden (all MLPs)
    float* ENC  = (float*)alloc((size_t)TT * DD * 4);  // later: Cf (in place)
    float* Pf   = (float*)alloc((size_t)TT * DD * 4);  // later: BBf (in place)
    bf16* Pb    = (bf16*)alloc((size_t)TT * DD * 2);
    bf16* dw1T  = ew1hT;   // alias: encoder split weights dead after GEMM1
    bf16* dw2T  = ew1lT;

    const dim3 blk(256);
    const dim3 blk8(512);

    // ---- prep ----
    splitx<<<TT * DD / 4 / 256, blk, 0, stream>>>(x, Xh, Xl);
    wtrans<true ><<<dim3(FF / 32, DD / 32), blk, 0, stream>>>(ew1, ew1hT, ew1lT, DD, FF);
    wtrans<false><<<dim3(DD / 32, FF / 32), blk, 0, stream>>>(ew2, ew2T, nullptr, FF, DD);
    wtrans<false><<<dim3(FF / 32, DD / 32), blk, 0, stream>>>(bw1, bw1T, nullptr, DD, FF);
    wtrans<false><<<dim3(DD / 32, FF / 32), blk, 0, stream>>>(bw2, bw2T, nullptr, FF, DD);
    wtrans<false><<<dim3(VV / 32, DD / 32), blk, 0, stream>>>(lmh, lmhT, nullptr, DD, VV);
    qvec<<<FF / 4, blk, 0, stream>>>(ew2, spw, qv);

    // ---- encoder GEMM1 (3-term split, relu, bf16 out, gate partials) ----
    mgemm_nt3<<<dim3(FF / 128, TT / 128), blk, 32768, stream>>>(
        Xh, Xl, ew1hT, ew1lT, Hb, GP, qv, TT, FF, DD);

    // ---- gate + scan ----
    gate2<<<TT / 4, blk, 0, stream>>>(x, spw, spb, GP, WG, MI);
    scan_kernel<<<1, blk, 0, stream>>>(MI, cu, ECS, META);

    // ---- encoder GEMM2: ENC = Hb @ ew2 + x (fp32 out) ----
    mgemm8<2, false, true, false><<<dim3(DD / 256, TT / 256), blk8, 131072, stream>>>(
        Hb, ew2T, x, nullptr, ENC, TT, DD, FF, nullptr);

    // ---- pack kept rows ----
    pack_kernel<<<TT / 4, blk, 0, stream>>>(ENC, WG, MI, ECS, cu, META, pem, Pf, Pb);

    // decoder weight transposes (into encoder-weight alias; after GEMM1)
    wtrans<false><<<dim3(FF / 32, DD / 32), blk, 0, stream>>>(dw1, dw1T, nullptr, DD, FF);
    wtrans<false><<<dim3(DD / 32, FF / 32), blk, 0, stream>>>(dw2, dw2T, nullptr, FF, DD);

    // ---- backbone (rowlim) ----
    mgemm8<1, true, false, true><<<dim3(FF / 256, TT / 256), blk8, 131072, stream>>>(
        Pb, bw1T, nullptr, Hb, nullptr, TT, FF, DD, META);
    mgemm8<2, false, true, true><<<dim3(DD / 256, TT / 256), blk8, 131072, stream>>>(
        Hb, bw2T, Pf, nullptr, Pf, TT, DD, FF, META);

    // ---- scatter-combine (Cf = ENC in place, Cb = Xl bf16) ----
    combine_kernel<<<TT / 4, blk, 0, stream>>>(ENC, Pf, MI, ECS, Xl);

    // ---- decoder ----
    mgemm8<1, true, false, false><<<dim3(FF / 256, TT / 256), blk8, 131072, stream>>>(
        Xl, dw1T, nullptr, Hb, nullptr, TT, FF, DD, nullptr);
    mgemm8<2, true, false, false><<<dim3(DD / 256, TT / 256), blk8, 131072, stream>>>(
        Hb, dw2T, ENC, Xh, nullptr, TT, DD, FF, nullptr);

    // ---- lm head ----
    mgemm8<0, false, true, false><<<dim3(VV / 256, TT / 256), blk8, 131072, stream>>>(
        Xh, lmhT, nullptr, nullptr, out, TT, VV, DD, nullptr);
}

// Round 6
// 860.840 us; speedup vs baseline: 37.3794x; 1.0042x over previous
//
#include <hip/hip_runtime.h>
#include <hip/hip_bf16.h>
#include <math.h>

static constexpr int TT = 16384;
static constexpr int DD = 1024;
static constexpr int FF = 2048;
static constexpr int VV = 4096;
static constexpr int CAP = 4096;       // borderline-token capacity
#define TAU 0.02f                      // |logit| flag threshold (~18 sigma of bf16 error)

using bf16 = __hip_bfloat16;
typedef __attribute__((ext_vector_type(8))) short bf16x8;
typedef __attribute__((ext_vector_type(4))) float f32x4;

__device__ inline void gload16(const void* g, void* l) {
    __builtin_amdgcn_global_load_lds(
        (const __attribute__((address_space(1))) void*)g,
        (__attribute__((address_space(3))) void*)l, 16, 0, 0);
}

// ===========================================================================
// 8-phase 256x256 MFMA GEMM (round-4 verified schedule).
// A [M,K] bf16 row-major, BT [N,K] bf16 (B^T). 512 thr = 8 waves (2M x 4N),
// per-wave out 128x64 (8 mf x 4 nf frags of 16x16x32). BK=64, 2 K-tiles/iter.
// LDS 128 KiB: buf{0,1} x {A[256][64] | B[256][64]}. Stage stream: half j,
// tile=j>>2, part order {B h0, B h1, A h0, A h1}; vmcnt(6) at phases A3/B3.
// GPART: fused gate partial dots sum_c relu(O[r][c])*qv[c] -> 32 slots.
// ===========================================================================
template<int EPI /*0 none,1 relu,2 +X*/, bool WB16, bool WF32, bool ROWLIM, bool GPART>
__global__ __launch_bounds__(512, 2)
void mgemm8(const bf16* __restrict__ A, const bf16* __restrict__ BT,
            const float* __restrict__ X, bf16* __restrict__ Ob,
            float* __restrict__ Of, float* __restrict__ gpart,
            const float* __restrict__ qv,
            int M, int N, int K, const int* __restrict__ rowlim)
{
    if constexpr (ROWLIM) { if ((int)blockIdx.y * 256 >= *rowlim) return; }
    const int m0 = blockIdx.y * 256, n0 = blockIdx.x * 256;

    extern __shared__ char smem[];   // 2 bufs x (A 32K | B 32K) = 128 KiB

    const int tid = threadIdx.x;
    const int wv = tid >> 6, ln = tid & 63;
    const int wm = wv >> 2, wn = wv & 3;
    const int lr = ln & 15, lk = ln >> 4;
    const int swz = (lr & 7) << 4;

    const bf16* Ag = A  + (size_t)m0 * K;
    const bf16* Bg = BT + (size_t)n0 * K;

    const int NT = K >> 6;
    const int NI = NT >> 1;

    const int aoff0 = (wm * 128 + lr) * 128;
    const int boff0 = 32768 + (wn * 64 + lr) * 128;
    const int cb0 = (lk * 16) ^ swz;
    const int cb1 = (64 + lk * 16) ^ swz;

    auto STAGE = [&](const bf16* g, int h, int kt, int buf, int op) {
        const int r = ln >> 3;
        const int c = ((ln & 7) ^ r) * 8;
        const bf16* s = g + (size_t)(h * 128 + wv * 16 + r) * K + kt * 64 + c;
        char* d = smem + buf * 65536 + op * 32768 + h * 16384 + wv * 2048;
        gload16(s, d);
        gload16(s + (size_t)8 * K, d + 1024);
    };
    auto stage_j = [&](int j) {
        const int tile = j >> 2;
        if (tile >= NT) return;
        const int part = j & 3;
        const int buf = tile & 1;
        if (part < 2) STAGE(Bg, part, tile, buf, 1);
        else          STAGE(Ag, part - 2, tile, buf, 0);
    };

    bf16x8 afr[2][2], bfr[4][2];
    f32x4 acc[8][4];
    #pragma unroll
    for (int m = 0; m < 8; ++m)
        #pragma unroll
        for (int n = 0; n < 4; ++n) acc[m][n] = (f32x4){0.f, 0.f, 0.f, 0.f};

#define DS_A(BUF, Q) do {                                                     \
    const char* _p = smem + (BUF) * 65536 + aoff0 + (Q) * 4096;               \
    afr[0][0] = *(const bf16x8*)(_p + cb0);                                   \
    afr[0][1] = *(const bf16x8*)(_p + cb1);                                   \
    afr[1][0] = *(const bf16x8*)(_p + 2048 + cb0);                            \
    afr[1][1] = *(const bf16x8*)(_p + 2048 + cb1);                            \
} while (0)

#define DS_B(BUF) do {                                                        \
    const char* _p = smem + (BUF) * 65536 + boff0;                            \
    _Pragma("unroll")                                                         \
    for (int nf = 0; nf < 4; ++nf) {                                          \
        bfr[nf][0] = *(const bf16x8*)(_p + nf * 2048 + cb0);                  \
        bfr[nf][1] = *(const bf16x8*)(_p + nf * 2048 + cb1);                  \
    }                                                                         \
} while (0)

#define MFMAQ(Q) do {                                                         \
    __builtin_amdgcn_s_setprio(1);                                            \
    _Pragma("unroll")                                                         \
    for (int m2 = 0; m2 < 2; ++m2)                                            \
        _Pragma("unroll")                                                     \
        for (int nf = 0; nf < 4; ++nf) {                                      \
            acc[(Q) * 2 + m2][nf] = __builtin_amdgcn_mfma_f32_16x16x32_bf16(  \
                afr[m2][0], bfr[nf][0], acc[(Q) * 2 + m2][nf], 0, 0, 0);      \
            acc[(Q) * 2 + m2][nf] = __builtin_amdgcn_mfma_f32_16x16x32_bf16(  \
                afr[m2][1], bfr[nf][1], acc[(Q) * 2 + m2][nf], 0, 0, 0);      \
        }                                                                     \
    __builtin_amdgcn_s_setprio(0);                                            \
} while (0)

// W: 0 = no wait, 1 = vmcnt(6), 2 = vmcnt(0)
#define PHASE(Q, BUF, DOB, J, W)                                              \
    {                                                                         \
        DS_A(BUF, Q);                                                         \
        if (DOB) DS_B(BUF);                                                   \
        stage_j(J);                                                           \
        if ((W) == 1)      asm volatile("s_waitcnt vmcnt(6)" ::: "memory");   \
        else if ((W) == 2) asm volatile("s_waitcnt vmcnt(0)" ::: "memory");   \
        __builtin_amdgcn_sched_barrier(0);                                    \
        __builtin_amdgcn_s_barrier();                                         \
        MFMAQ(Q);                                                             \
        __builtin_amdgcn_s_barrier();                                         \
    }

    STAGE(Bg, 0, 0, 0, 1); STAGE(Bg, 1, 0, 0, 1);
    STAGE(Ag, 0, 0, 0, 0); STAGE(Ag, 1, 0, 0, 0);
    asm volatile("s_waitcnt vmcnt(4)" ::: "memory");
    STAGE(Bg, 0, 1, 1, 1); STAGE(Bg, 1, 1, 1, 1);
    STAGE(Ag, 0, 1, 1, 0);
    asm volatile("s_waitcnt vmcnt(6)" ::: "memory");
    __builtin_amdgcn_sched_barrier(0);
    __builtin_amdgcn_s_barrier();

    for (int i = 0; i < NI; ++i) {
        const int jb = 7 + 8 * i;
        const bool last = (i + 1 == NI);
        PHASE(0, 0, true,  jb + 0, 0);
        PHASE(1, 0, false, jb + 1, 0);
        PHASE(2, 0, false, jb + 2, 0);
        PHASE(3, 0, false, jb + 3, last ? 2 : 1);
        PHASE(0, 1, true,  jb + 4, 0);
        PHASE(1, 1, false, jb + 5, 0);
        PHASE(2, 1, false, jb + 6, 0);
        PHASE(3, 1, false, jb + 7, last ? 0 : 1);
    }

#undef PHASE
#undef MFMAQ
#undef DS_B
#undef DS_A

    if constexpr (GPART) {
        float qvv[4];
        #pragma unroll
        for (int nf = 0; nf < 4; ++nf) qvv[nf] = qv[n0 + wn * 64 + nf * 16 + lr];
        #pragma unroll
        for (int mf = 0; mf < 8; ++mf)
            #pragma unroll
            for (int rr = 0; rr < 4; ++rr) {
                float s = 0.f;
                #pragma unroll
                for (int nf = 0; nf < 4; ++nf) s += fmaxf(acc[mf][nf][rr], 0.f) * qvv[nf];
                s += __shfl_xor(s, 1, 64); s += __shfl_xor(s, 2, 64);
                s += __shfl_xor(s, 4, 64); s += __shfl_xor(s, 8, 64);
                if (lr == 0)
                    gpart[(size_t)(blockIdx.x * 4 + wn) * M +
                          (m0 + wm * 128 + mf * 16 + lk * 4 + rr)] = s;
            }
    }

    #pragma unroll
    for (int mf = 0; mf < 8; ++mf)
        #pragma unroll
        for (int nf = 0; nf < 4; ++nf)
            #pragma unroll
            for (int rr = 0; rr < 4; ++rr) {
                const int row = m0 + wm * 128 + mf * 16 + lk * 4 + rr;
                const int col = n0 + wn * 64 + nf * 16 + lr;
                float v = acc[mf][nf][rr];
                if constexpr (EPI == 1) v = fmaxf(v, 0.f);
                if constexpr (EPI == 2) v += X[(size_t)row * N + col];
                if constexpr (WB16) Ob[(size_t)row * N + col] = __float2bfloat16(v);
                if constexpr (WF32) Of[(size_t)row * N + col] = v;
            }
}

// ---------------------------------------------------------------------------
__global__ void wtrans(const float* __restrict__ W, bf16* __restrict__ Th,
                       int R, int C)
{
    __shared__ float tile[32][33];
    const int tx = threadIdx.x & 31, ty = threadIdx.x >> 5;
    const int rb = blockIdx.y * 32, cb = blockIdx.x * 32;
    #pragma unroll
    for (int i = 0; i < 32; i += 8)
        tile[ty + i][tx] = W[(size_t)(rb + ty + i) * C + cb + tx];
    __syncthreads();
    #pragma unroll
    for (int i = 0; i < 32; i += 8)
        Th[(size_t)(cb + ty + i) * R + rb + tx] = __float2bfloat16(tile[tx][ty + i]);
}

__global__ void castx(const float* __restrict__ x, bf16* __restrict__ xb)
{
    const int i = blockIdx.x * 256 + threadIdx.x;
    const float4 v = ((const float4*)x)[i];
    xb[i * 4 + 0] = __float2bfloat16(v.x);
    xb[i * 4 + 1] = __float2bfloat16(v.y);
    xb[i * 4 + 2] = __float2bfloat16(v.z);
    xb[i * 4 + 3] = __float2bfloat16(v.w);
}

// q[f] = sum_d w2[f][d] * sp[d]
__global__ void qvec(const float* __restrict__ w2, const float* __restrict__ sp,
                     float* __restrict__ q)
{
    const int f  = blockIdx.x * 4 + (threadIdx.x >> 6);
    const int ln = threadIdx.x & 63;
    float s = 0.f;
    const float* row = w2 + (size_t)f * DD;
    for (int k = ln; k < DD; k += 64) s += row[k] * sp[k];
    #pragma unroll
    for (int off = 32; off > 0; off >>= 1) s += __shfl_xor(s, off, 64);
    if (ln == 0) q[f] = s;
}

// gate: logit~ = x·sp + Σ gpart + b; flag |logit~|<TAU for exact recompute
__global__ void gate2(const float* __restrict__ x, const float* __restrict__ spw,
                      const float* __restrict__ spb, const float* __restrict__ gpart,
                      float* __restrict__ w, int* __restrict__ mi,
                      float* __restrict__ sx, int* __restrict__ flags,
                      int* __restrict__ cnt)
{
    const int t  = blockIdx.x * 4 + (threadIdx.x >> 6);
    const int ln = threadIdx.x & 63;
    float s = 0.f;
    const float* row = x + (size_t)t * DD;
    for (int k = ln; k < DD; k += 64) s += row[k] * spw[k];
    #pragma unroll
    for (int off = 32; off > 0; off >>= 1) s += __shfl_xor(s, off, 64);
    float g = (ln < 32) ? gpart[(size_t)ln * TT + t] : 0.f;
    #pragma unroll
    for (int off = 32; off > 0; off >>= 1) g += __shfl_xor(g, off, 64);
    if (ln == 0) {
        const float logit = s + g + spb[0];
        const float sg = 1.f / (1.f + expf(-logit));
        w[t]  = sg;
        mi[t] = (sg >= 0.5f) ? 1 : 0;
        sx[t] = s;
        if (fabsf(logit) < TAU) {
            const int i = atomicAdd(cnt, 1);
            if (i < CAP) flags[i] = t;
        }
    }
}

// exact fp32 GEMV for flagged tokens: gpf[fc][slot] = Σ_{f in chunk} relu(x_t·w1_f)·q_f
__global__ void fixgemv(const float* __restrict__ x, const float* __restrict__ w1,
                        const float* __restrict__ qv, const int* __restrict__ flags,
                        const int* __restrict__ cnt, float* __restrict__ gpf)
{
    const int nb = min(*cnt, CAP);
    const int t0 = blockIdx.y * 16;
    if (t0 >= nb) return;
    const int ntk = min(16, nb - t0);
    const int f = blockIdx.x * 256 + threadIdx.x;
    const float qf = qv[f];
    __shared__ float xs[16][64];
    __shared__ float red[4][16];
    float acc[16];
    #pragma unroll
    for (int tk = 0; tk < 16; ++tk) acc[tk] = 0.f;

    for (int d0 = 0; d0 < DD; d0 += 64) {
        __syncthreads();
        for (int i = threadIdx.x; i < 16 * 64; i += 256) {
            const int tk = i >> 6, dd = i & 63;
            xs[tk][dd] = (tk < ntk)
                ? x[(size_t)flags[t0 + tk] * DD + d0 + dd] : 0.f;
        }
        __syncthreads();
        for (int dd = 0; dd < 64; ++dd) {
            const float wv = w1[(size_t)(d0 + dd) * FF + f];
            #pragma unroll
            for (int tk = 0; tk < 16; ++tk) acc[tk] += xs[tk][dd] * wv;
        }
    }
    const int wv_ = threadIdx.x >> 6, ln = threadIdx.x & 63;
    #pragma unroll
    for (int tk = 0; tk < 16; ++tk) {
        float v = fmaxf(acc[tk], 0.f) * qf;
        #pragma unroll
        for (int off = 32; off > 0; off >>= 1) v += __shfl_xor(v, off, 64);
        if (ln == 0) red[wv_][tk] = v;
    }
    __syncthreads();
    if (threadIdx.x < 16)
        gpf[(size_t)blockIdx.x * CAP + t0 + threadIdx.x] =
            red[0][threadIdx.x] + red[1][threadIdx.x] +
            red[2][threadIdx.x] + red[3][threadIdx.x];
}

// resolve flagged tokens with the exact logit
__global__ void fixres(const float* __restrict__ sx, const float* __restrict__ spb,
                       const float* __restrict__ gpf, const int* __restrict__ flags,
                       const int* __restrict__ cnt, float* __restrict__ w,
                       int* __restrict__ mi)
{
    const int nb = min(*cnt, CAP);
    for (int i = blockIdx.x * 256 + threadIdx.x; i < nb; i += gridDim.x * 256) {
        const int t = flags[i];
        float s = sx[t] + spb[0];
        #pragma unroll
        for (int fc = 0; fc < 8; ++fc) s += gpf[(size_t)fc * CAP + i];
        const float sg = 1.f / (1.f + expf(-s));
        w[t]  = sg;
        mi[t] = (sg >= 0.5f) ? 1 : 0;
    }
}

__global__ void scan_kernel(const int* __restrict__ mi, const int* __restrict__ cu,
                            int* __restrict__ ecs, int* __restrict__ meta)
{
    __shared__ int sums[256];
    const int tid  = threadIdx.x;
    const int base = tid * 64;
    int s = 0;
    for (int i = 0; i < 64; ++i) s += mi[base + i];
    sums[tid] = s;
    __syncthreads();
    for (int off = 1; off < 256; off <<= 1) {
        int v = (tid >= off) ? sums[tid - off] : 0;
        __syncthreads();
        sums[tid] += v;
        __syncthreads();
    }
    int run = (tid == 0) ? 0 : sums[tid - 1];
    for (int i = 0; i < 64; ++i) { ecs[base + i] = run; run += mi[base + i]; }
    if (tid == 255) meta[0] = sums[255];
    if (tid < 4) {
        const int idx = cu[tid];
        const int tc = idx >> 6, rem = idx & 63;
        int e = (tc == 0) ? 0 : sums[tc - 1];
        for (int i = 0; i < rem; ++i) e += mi[tc * 64 + i];
        meta[1 + tid] = e;
    }
}

__global__ void pack_kernel(const float* __restrict__ enc, const float* __restrict__ w,
                            const int* __restrict__ mi, const int* __restrict__ ecs,
                            const int* __restrict__ cu, const int* __restrict__ meta,
                            const float* __restrict__ pos_emb,
                            float* __restrict__ Pf, bf16* __restrict__ Pb)
{
    const int t    = blockIdx.x * 4 + (threadIdx.x >> 6);
    const int lane = threadIdx.x & 63;
    if (!mi[t]) return;
    const int e = ecs[t];
    int seg = 0;
    #pragma unroll
    for (int ss = 1; ss < 4; ++ss) if (t >= cu[ss]) seg = ss;
    const int np = e - meta[1 + seg];
    const float wt = w[t];
    const float4* src = (const float4*)(enc + (size_t)t * DD);
    const float4* pe  = (const float4*)(pos_emb + (size_t)np * DD);
    float4* dstf = (float4*)(Pf + (size_t)e * DD);
    bf16*   dstb = Pb + (size_t)e * DD;
    for (int c = lane; c < DD / 4; c += 64) {
        float4 v = src[c], p = pe[c];
        v.x = v.x * wt + p.x; v.y = v.y * wt + p.y;
        v.z = v.z * wt + p.z; v.w = v.w * wt + p.w;
        dstf[c] = v;
        dstb[c * 4 + 0] = __float2bfloat16(v.x);
        dstb[c * 4 + 1] = __float2bfloat16(v.y);
        dstb[c * 4 + 2] = __float2bfloat16(v.z);
        dstb[c * 4 + 3] = __float2bfloat16(v.w);
    }
}

__global__ void combine_kernel(float* __restrict__ ENC, const float* __restrict__ BBf,
                               const int* __restrict__ mi, const int* __restrict__ ecs,
                               bf16* __restrict__ Cb)
{
    const int t    = blockIdx.x * 4 + (threadIdx.x >> 6);
    const int lane = threadIdx.x & 63;
    const bool kept = mi[t] != 0;
    const float4* src = kept ? (const float4*)(BBf + (size_t)ecs[t] * DD)
                             : (const float4*)(ENC + (size_t)t * DD);
    float4* dstf = (float4*)(ENC + (size_t)t * DD);
    bf16*   dstb = Cb + (size_t)t * DD;
    for (int c = lane; c < DD / 4; c += 64) {
        const float4 v = src[c];
        if (kept) dstf[c] = v;
        dstb[c * 4 + 0] = __float2bfloat16(v.x);
        dstb[c * 4 + 1] = __float2bfloat16(v.y);
        dstb[c * 4 + 2] = __float2bfloat16(v.z);
        dstb[c * 4 + 3] = __float2bfloat16(v.w);
    }
}

// ---------------------------------------------------------------------------
extern "C" void kernel_launch(void* const* d_in, const int* in_sizes, int n_in,
                              void* d_out, int out_size, void* d_ws, size_t ws_size,
                              hipStream_t stream)
{
    (void)in_sizes; (void)n_in; (void)out_size; (void)ws_size;
    const float* x   = (const float*)d_in[0];
    const float* ew1 = (const float*)d_in[1];
    const float* ew2 = (const float*)d_in[2];
    const float* bw1 = (const float*)d_in[3];
    const float* bw2 = (const float*)d_in[4];
    const float* dw1 = (const float*)d_in[5];
    const float* dw2 = (const float*)d_in[6];
    const float* spw = (const float*)d_in[7];
    const float* spb = (const float*)d_in[8];
    const float* pem = (const float*)d_in[9];
    const float* lmh = (const float*)d_in[10];
    const int*   cu  = (const int*)d_in[11];
    float* out = (float*)d_out;

    (void)hipFuncSetAttribute((const void*)mgemm8<1, true, false, false, true>,
                              hipFuncAttributeMaxDynamicSharedMemorySize, 131072);
    (void)hipFuncSetAttribute((const void*)mgemm8<2, false, true, false, false>,
                              hipFuncAttributeMaxDynamicSharedMemorySize, 131072);
    (void)hipFuncSetAttribute((const void*)mgemm8<1, true, false, true, false>,
                              hipFuncAttributeMaxDynamicSharedMemorySize, 131072);
    (void)hipFuncSetAttribute((const void*)mgemm8<2, false, true, true, false>,
                              hipFuncAttributeMaxDynamicSharedMemorySize, 131072);
    (void)hipFuncSetAttribute((const void*)mgemm8<1, true, false, false, false>,
                              hipFuncAttributeMaxDynamicSharedMemorySize, 131072);
    (void)hipFuncSetAttribute((const void*)mgemm8<2, true, false, false, false>,
                              hipFuncAttributeMaxDynamicSharedMemorySize, 131072);
    (void)hipFuncSetAttribute((const void*)mgemm8<0, false, true, false, false>,
                              hipFuncAttributeMaxDynamicSharedMemorySize, 131072);

    // ---- workspace carve (~291 MB) ----
    char* w = (char*)d_ws;
    auto alloc = [&](size_t bytes) { char* p = w; w += bytes; return p; };
    bf16* ew1T = (bf16*)alloc((size_t)FF * DD * 2);
    bf16* ew2T = (bf16*)alloc((size_t)DD * FF * 2);
    bf16* bw1T = (bf16*)alloc((size_t)FF * DD * 2);
    bf16* bw2T = (bf16*)alloc((size_t)DD * FF * 2);
    bf16* dw1T = (bf16*)alloc((size_t)FF * DD * 2);
    bf16* dw2T = (bf16*)alloc((size_t)DD * FF * 2);
    bf16* lmhT = (bf16*)alloc((size_t)VV * DD * 2);
    float* qv  = (float*)alloc((size_t)FF * 4);
    float* GP  = (float*)alloc((size_t)32 * TT * 4);
    float* WG  = (float*)alloc((size_t)TT * 4);
    int*  MI   = (int*)alloc((size_t)TT * 4);
    int*  ECS  = (int*)alloc((size_t)TT * 4);
    int*  META = (int*)alloc(64);
    float* SX  = (float*)alloc((size_t)TT * 4);
    int*  FLAGS= (int*)alloc((size_t)CAP * 4);
    int*  CNT  = (int*)alloc(64);
    float* GPF = (float*)alloc((size_t)8 * CAP * 4);
    bf16* Xb   = (bf16*)alloc((size_t)TT * DD * 2);   // enc1 A; reused as Cb
    bf16* Hb   = (bf16*)alloc((size_t)TT * FF * 2);   // hidden (all MLPs)
    float* ENC = (float*)alloc((size_t)TT * DD * 4);  // later: Cf (in place)
    float* Pf  = (float*)alloc((size_t)TT * DD * 4);  // later: BBf (in place)
    bf16* Pb   = (bf16*)alloc((size_t)TT * DD * 2);   // reused as DECb
    bf16* Cb   = Xb;
    bf16* DECb = Pb;

    const dim3 blk(256);
    const dim3 blk8(512);

    (void)hipMemsetAsync(CNT, 0, 4, stream);

    // ---- prep ----
    castx<<<TT * DD / 4 / 256, blk, 0, stream>>>(x, Xb);
    wtrans<<<dim3(FF / 32, DD / 32), blk, 0, stream>>>(ew1, ew1T, DD, FF);
    wtrans<<<dim3(DD / 32, FF / 32), blk, 0, stream>>>(ew2, ew2T, FF, DD);
    wtrans<<<dim3(FF / 32, DD / 32), blk, 0, stream>>>(bw1, bw1T, DD, FF);
    wtrans<<<dim3(DD / 32, FF / 32), blk, 0, stream>>>(bw2, bw2T, FF, DD);
    wtrans<<<dim3(FF / 32, DD / 32), blk, 0, stream>>>(dw1, dw1T, DD, FF);
    wtrans<<<dim3(DD / 32, FF / 32), blk, 0, stream>>>(dw2, dw2T, FF, DD);
    wtrans<<<dim3(VV / 32, DD / 32), blk, 0, stream>>>(lmh, lmhT, DD, VV);
    qvec<<<FF / 4, blk, 0, stream>>>(ew2, spw, qv);

    // ---- encoder GEMM1: plain bf16 8-phase + fused gate partials ----
    mgemm8<1, true, false, false, true><<<dim3(FF / 256, TT / 256), blk8, 131072, stream>>>(
        Xb, ew1T, nullptr, Hb, nullptr, GP, qv, TT, FF, DD, nullptr);

    // ---- gate (approx) + borderline fixup + scan ----
    gate2<<<TT / 4, blk, 0, stream>>>(x, spw, spb, GP, WG, MI, SX, FLAGS, CNT);
    fixgemv<<<dim3(8, CAP / 16), blk, 0, stream>>>(x, ew1, qv, FLAGS, CNT, GPF);
    fixres<<<16, blk, 0, stream>>>(SX, spb, GPF, FLAGS, CNT, WG, MI);
    scan_kernel<<<1, blk, 0, stream>>>(MI, cu, ECS, META);

    // ---- encoder GEMM2: ENC = Hb @ ew2 + x (fp32 out) ----
    mgemm8<2, false, true, false, false><<<dim3(DD / 256, TT / 256), blk8, 131072, stream>>>(
        Hb, ew2T, x, nullptr, ENC, nullptr, nullptr, TT, DD, FF, nullptr);

    // ---- pack kept rows ----
    pack_kernel<<<TT / 4, blk, 0, stream>>>(ENC, WG, MI, ECS, cu, META, pem, Pf, Pb);

    // ---- backbone (rowlim) ----
    mgemm8<1, true, false, true, false><<<dim3(FF / 256, TT / 256), blk8, 131072, stream>>>(
        Pb, bw1T, nullptr, Hb, nullptr, nullptr, nullptr, TT, FF, DD, META);
    mgemm8<2, false, true, true, false><<<dim3(DD / 256, TT / 256), blk8, 131072, stream>>>(
        Hb, bw2T, Pf, nullptr, Pf, nullptr, nullptr, TT, DD, FF, META);

    // ---- scatter-combine (Cf = ENC in place, Cb bf16) ----
    combine_kernel<<<TT / 4, blk, 0, stream>>>(ENC, Pf, MI, ECS, Cb);

    // ---- decoder ----
    mgemm8<1, true, false, false, false><<<dim3(FF / 256, TT / 256), blk8, 131072, stream>>>(
        Cb, dw1T, nullptr, Hb, nullptr, nullptr, nullptr, TT, FF, DD, nullptr);
    mgemm8<2, true, false, false, false><<<dim3(DD / 256, TT / 256), blk8, 131072, stream>>>(
        Hb, dw2T, ENC, DECb, nullptr, nullptr, nullptr, TT, DD, FF, nullptr);

    // ---- lm head ----
    mgemm8<0, false, true, false, false><<<dim3(VV / 256, TT / 256), blk8, 131072, stream>>>(
        DECb, lmhT, nullptr, nullptr, out, nullptr, nullptr, TT, VV, DD, nullptr);
}

// Round 7
// 765.691 us; speedup vs baseline: 42.0244x; 1.1243x over previous
//
#include <hip/hip_runtime.h>
#include <hip/hip_bf16.h>
#include <math.h>

static constexpr int TT = 16384;
static constexpr int DD = 1024;
static constexpr int FF = 2048;
static constexpr int VV = 4096;
static constexpr int CAP = 1024;       // borderline-token capacity (exp ~190)
#define TAU 0.02f                      // |logit| flag threshold

using bf16 = __hip_bfloat16;
typedef __attribute__((ext_vector_type(8))) short bf16x8;
typedef __attribute__((ext_vector_type(4))) float f32x4;

__device__ inline void gload16(const void* g, void* l) {
    __builtin_amdgcn_global_load_lds(
        (const __attribute__((address_space(1))) void*)g,
        (__attribute__((address_space(3))) void*)l, 16, 0, 0);
}

// ===========================================================================
// 8-phase 256x256 MFMA GEMM (round-4 verified schedule).
// A [M,K] bf16 row-major, BT [N,K] bf16 (B^T). 512 thr = 8 waves (2M x 4N),
// per-wave out 128x64 (8 mf x 4 nf frags of 16x16x32). BK=64, 2 K-tiles/iter.
// LDS 128 KiB: buf{0,1} x {A[256][64] | B[256][64]}. Stage stream: half j,
// tile=j>>2, part order {B h0, B h1, A h0, A h1}; vmcnt(6) at phases A3/B3.
// GPART: fused gate partial dots sum_c relu(O[r][c])*qv[c] -> 32 slots.
// ===========================================================================
template<int EPI /*0 none,1 relu,2 +X*/, bool WB16, bool WF32, bool ROWLIM, bool GPART>
__global__ __launch_bounds__(512, 2)
void mgemm8(const bf16* __restrict__ A, const bf16* __restrict__ BT,
            const float* __restrict__ X, bf16* __restrict__ Ob,
            float* __restrict__ Of, float* __restrict__ gpart,
            const float* __restrict__ qv,
            int M, int N, int K, const int* __restrict__ rowlim)
{
    if constexpr (ROWLIM) { if ((int)blockIdx.y * 256 >= *rowlim) return; }
    const int m0 = blockIdx.y * 256, n0 = blockIdx.x * 256;

    extern __shared__ char smem[];   // 2 bufs x (A 32K | B 32K) = 128 KiB

    const int tid = threadIdx.x;
    const int wv = tid >> 6, ln = tid & 63;
    const int wm = wv >> 2, wn = wv & 3;
    const int lr = ln & 15, lk = ln >> 4;
    const int swz = (lr & 7) << 4;

    const bf16* Ag = A  + (size_t)m0 * K;
    const bf16* Bg = BT + (size_t)n0 * K;

    const int NT = K >> 6;
    const int NI = NT >> 1;

    const int aoff0 = (wm * 128 + lr) * 128;
    const int boff0 = 32768 + (wn * 64 + lr) * 128;
    const int cb0 = (lk * 16) ^ swz;
    const int cb1 = (64 + lk * 16) ^ swz;

    auto STAGE = [&](const bf16* g, int h, int kt, int buf, int op) {
        const int r = ln >> 3;
        const int c = ((ln & 7) ^ r) * 8;
        const bf16* s = g + (size_t)(h * 128 + wv * 16 + r) * K + kt * 64 + c;
        char* d = smem + buf * 65536 + op * 32768 + h * 16384 + wv * 2048;
        gload16(s, d);
        gload16(s + (size_t)8 * K, d + 1024);
    };
    auto stage_j = [&](int j) {
        const int tile = j >> 2;
        if (tile >= NT) return;
        const int part = j & 3;
        const int buf = tile & 1;
        if (part < 2) STAGE(Bg, part, tile, buf, 1);
        else          STAGE(Ag, part - 2, tile, buf, 0);
    };

    bf16x8 afr[2][2], bfr[4][2];
    f32x4 acc[8][4];
    #pragma unroll
    for (int m = 0; m < 8; ++m)
        #pragma unroll
        for (int n = 0; n < 4; ++n) acc[m][n] = (f32x4){0.f, 0.f, 0.f, 0.f};

#define DS_A(BUF, Q) do {                                                     \
    const char* _p = smem + (BUF) * 65536 + aoff0 + (Q) * 4096;               \
    afr[0][0] = *(const bf16x8*)(_p + cb0);                                   \
    afr[0][1] = *(const bf16x8*)(_p + cb1);                                   \
    afr[1][0] = *(const bf16x8*)(_p + 2048 + cb0);                            \
    afr[1][1] = *(const bf16x8*)(_p + 2048 + cb1);                            \
} while (0)

#define DS_B(BUF) do {                                                        \
    const char* _p = smem + (BUF) * 65536 + boff0;                            \
    _Pragma("unroll")                                                         \
    for (int nf = 0; nf < 4; ++nf) {                                          \
        bfr[nf][0] = *(const bf16x8*)(_p + nf * 2048 + cb0);                  \
        bfr[nf][1] = *(const bf16x8*)(_p + nf * 2048 + cb1);                  \
    }                                                                         \
} while (0)

#define MFMAQ(Q) do {                                                         \
    __builtin_amdgcn_s_setprio(1);                                            \
    _Pragma("unroll")                                                         \
    for (int m2 = 0; m2 < 2; ++m2)                                            \
        _Pragma("unroll")                                                     \
        for (int nf = 0; nf < 4; ++nf) {                                      \
            acc[(Q) * 2 + m2][nf] = __builtin_amdgcn_mfma_f32_16x16x32_bf16(  \
                afr[m2][0], bfr[nf][0], acc[(Q) * 2 + m2][nf], 0, 0, 0);      \
            acc[(Q) * 2 + m2][nf] = __builtin_amdgcn_mfma_f32_16x16x32_bf16(  \
                afr[m2][1], bfr[nf][1], acc[(Q) * 2 + m2][nf], 0, 0, 0);      \
        }                                                                     \
    __builtin_amdgcn_s_setprio(0);                                            \
} while (0)

// W: 0 = no wait, 1 = vmcnt(6), 2 = vmcnt(0)
#define PHASE(Q, BUF, DOB, J, W)                                              \
    {                                                                         \
        DS_A(BUF, Q);                                                         \
        if (DOB) DS_B(BUF);                                                   \
        stage_j(J);                                                           \
        if ((W) == 1)      asm volatile("s_waitcnt vmcnt(6)" ::: "memory");   \
        else if ((W) == 2) asm volatile("s_waitcnt vmcnt(0)" ::: "memory");   \
        __builtin_amdgcn_sched_barrier(0);                                    \
        __builtin_amdgcn_s_barrier();                                         \
        MFMAQ(Q);                                                             \
        __builtin_amdgcn_s_barrier();                                         \
    }

    STAGE(Bg, 0, 0, 0, 1); STAGE(Bg, 1, 0, 0, 1);
    STAGE(Ag, 0, 0, 0, 0); STAGE(Ag, 1, 0, 0, 0);
    asm volatile("s_waitcnt vmcnt(4)" ::: "memory");
    STAGE(Bg, 0, 1, 1, 1); STAGE(Bg, 1, 1, 1, 1);
    STAGE(Ag, 0, 1, 1, 0);
    asm volatile("s_waitcnt vmcnt(6)" ::: "memory");
    __builtin_amdgcn_sched_barrier(0);
    __builtin_amdgcn_s_barrier();

    for (int i = 0; i < NI; ++i) {
        const int jb = 7 + 8 * i;
        const bool last = (i + 1 == NI);
        PHASE(0, 0, true,  jb + 0, 0);
        PHASE(1, 0, false, jb + 1, 0);
        PHASE(2, 0, false, jb + 2, 0);
        PHASE(3, 0, false, jb + 3, last ? 2 : 1);
        PHASE(0, 1, true,  jb + 4, 0);
        PHASE(1, 1, false, jb + 5, 0);
        PHASE(2, 1, false, jb + 6, 0);
        PHASE(3, 1, false, jb + 7, last ? 0 : 1);
    }

#undef PHASE
#undef MFMAQ
#undef DS_B
#undef DS_A

    if constexpr (GPART) {
        float qvv[4];
        #pragma unroll
        for (int nf = 0; nf < 4; ++nf) qvv[nf] = qv[n0 + wn * 64 + nf * 16 + lr];
        #pragma unroll
        for (int mf = 0; mf < 8; ++mf)
            #pragma unroll
            for (int rr = 0; rr < 4; ++rr) {
                float s = 0.f;
                #pragma unroll
                for (int nf = 0; nf < 4; ++nf) s += fmaxf(acc[mf][nf][rr], 0.f) * qvv[nf];
                s += __shfl_xor(s, 1, 64); s += __shfl_xor(s, 2, 64);
                s += __shfl_xor(s, 4, 64); s += __shfl_xor(s, 8, 64);
                if (lr == 0)
                    gpart[(size_t)(blockIdx.x * 4 + wn) * M +
                          (m0 + wm * 128 + mf * 16 + lk * 4 + rr)] = s;
            }
    }

    #pragma unroll
    for (int mf = 0; mf < 8; ++mf)
        #pragma unroll
        for (int nf = 0; nf < 4; ++nf)
            #pragma unroll
            for (int rr = 0; rr < 4; ++rr) {
                const int row = m0 + wm * 128 + mf * 16 + lk * 4 + rr;
                const int col = n0 + wn * 64 + nf * 16 + lr;
                float v = acc[mf][nf][rr];
                if constexpr (EPI == 1) v = fmaxf(v, 0.f);
                if constexpr (EPI == 2) v += X[(size_t)row * N + col];
                if constexpr (WB16) Ob[(size_t)row * N + col] = __float2bfloat16(v);
                if constexpr (WF32) Of[(size_t)row * N + col] = v;
            }
}

// ---------------------------------------------------------------------------
// fused weight transposes: 6x [DD<->FF] + lmh [DD][VV] -> bf16 B^T layouts
// ---------------------------------------------------------------------------
__global__ void wtrans_all(const float* __restrict__ e1, const float* __restrict__ e2,
                           const float* __restrict__ b1, const float* __restrict__ b2,
                           const float* __restrict__ d1, const float* __restrict__ d2,
                           const float* __restrict__ lm,
                           bf16* __restrict__ e1T, bf16* __restrict__ e2T,
                           bf16* __restrict__ b1T, bf16* __restrict__ b2T,
                           bf16* __restrict__ d1T, bf16* __restrict__ d2T,
                           bf16* __restrict__ lmT)
{
    int bid = blockIdx.x;
    const float* W; bf16* T; int R, C;
    if (bid < 12288) {
        const int m = bid >> 11;
        bid &= 2047;
        R = (m & 1) ? FF : DD;
        C = (m & 1) ? DD : FF;
        switch (m) {
            case 0:  W = e1; T = e1T; break;
            case 1:  W = e2; T = e2T; break;
            case 2:  W = b1; T = b1T; break;
            case 3:  W = b2; T = b2T; break;
            case 4:  W = d1; T = d1T; break;
            default: W = d2; T = d2T; break;
        }
    } else {
        bid -= 12288; W = lm; T = lmT; R = DD; C = VV;
    }
    const int tc = C >> 5;
    const int cb = (bid % tc) * 32, rb = (bid / tc) * 32;

    __shared__ float tile[32][33];
    const int tx = threadIdx.x & 31, ty = threadIdx.x >> 5;
    #pragma unroll
    for (int i = 0; i < 32; i += 8)
        tile[ty + i][tx] = W[(size_t)(rb + ty + i) * C + cb + tx];
    __syncthreads();
    #pragma unroll
    for (int i = 0; i < 32; i += 8)
        T[(size_t)(cb + ty + i) * R + rb + tx] = __float2bfloat16(tile[tx][ty + i]);
}

// x -> bf16 cast + fused row-dot sx[t] = x[t]·spw  (one wave per token)
__global__ void castx2(const float* __restrict__ x, const float* __restrict__ spw,
                       bf16* __restrict__ xb, float* __restrict__ sx)
{
    const int t  = blockIdx.x * 4 + (threadIdx.x >> 6);
    const int ln = threadIdx.x & 63;
    const float4* row = (const float4*)(x + (size_t)t * DD);
    const float4* sp4 = (const float4*)spw;
    bf16* dst = xb + (size_t)t * DD;
    float s = 0.f;
    #pragma unroll
    for (int q = 0; q < 4; ++q) {
        const int c = q * 64 + ln;
        const float4 v = row[c], p = sp4[c];
        s += v.x * p.x + v.y * p.y + v.z * p.z + v.w * p.w;
        dst[c * 4 + 0] = __float2bfloat16(v.x);
        dst[c * 4 + 1] = __float2bfloat16(v.y);
        dst[c * 4 + 2] = __float2bfloat16(v.z);
        dst[c * 4 + 3] = __float2bfloat16(v.w);
    }
    #pragma unroll
    for (int off = 32; off > 0; off >>= 1) s += __shfl_xor(s, off, 64);
    if (ln == 0) sx[t] = s;
}

// q[f] = sum_d w2[f][d] * sp[d]
__global__ void qvec(const float* __restrict__ w2, const float* __restrict__ sp,
                     float* __restrict__ q)
{
    const int f  = blockIdx.x * 4 + (threadIdx.x >> 6);
    const int ln = threadIdx.x & 63;
    float s = 0.f;
    const float* row = w2 + (size_t)f * DD;
    for (int k = ln; k < DD; k += 64) s += row[k] * sp[k];
    #pragma unroll
    for (int off = 32; off > 0; off >>= 1) s += __shfl_xor(s, off, 64);
    if (ln == 0) q[f] = s;
}

// gate: logit~ = sx + Σ gpart + b ; flag |logit~| < TAU (thread per token)
__global__ void gate2(const float* __restrict__ sx, const float* __restrict__ spb,
                      const float* __restrict__ gpart, float* __restrict__ w,
                      int* __restrict__ mi, int* __restrict__ flags,
                      int* __restrict__ cnt)
{
    const int t = blockIdx.x * 256 + threadIdx.x;
    float s = sx[t] + spb[0];
    #pragma unroll
    for (int j = 0; j < 32; ++j) s += gpart[(size_t)j * TT + t];
    const float sg = 1.f / (1.f + expf(-s));
    w[t]  = sg;
    mi[t] = (sg >= 0.5f) ? 1 : 0;
    if (fabsf(s) < TAU) {
        const int i = atomicAdd(cnt, 1);
        if (i < CAP) flags[i] = t;
    }
}

// split-K exact partial dots for flagged tokens:
// Hpart[kc][i][f] = Σ_{d in chunk kc} x[flags[i]][d] * w1[d][f]
// grid (FF/256, 4, CAP/32), 256 thr (1 f each, 32 token-accumulators)
__global__ __launch_bounds__(256)
void fixh(const float* __restrict__ x, const float* __restrict__ w1,
          const int* __restrict__ flags, const int* __restrict__ cnt,
          float* __restrict__ Hpart)
{
    const int nb = min(*cnt, CAP);
    const int t0 = blockIdx.z * 32;
    if (t0 >= nb) return;
    const int ntk = min(32, nb - t0);
    const int f  = blockIdx.x * 256 + threadIdx.x;
    const int d0 = blockIdx.y * 256;

    __shared__ float xs[32][256];
    for (int i = threadIdx.x; i < 32 * 64; i += 256) {
        const int tk = i >> 6, dq = i & 63;
        float4 v = (tk < ntk)
            ? *(const float4*)&x[(size_t)flags[t0 + tk] * DD + d0 + dq * 4]
            : make_float4(0.f, 0.f, 0.f, 0.f);
        *(float4*)&xs[tk][dq * 4] = v;
    }
    __syncthreads();

    float acc[32];
    #pragma unroll
    for (int tk = 0; tk < 32; ++tk) acc[tk] = 0.f;
    for (int dd = 0; dd < 256; ++dd) {
        const float wv = w1[(size_t)(d0 + dd) * FF + f];
        #pragma unroll
        for (int tk = 0; tk < 32; ++tk) acc[tk] += xs[tk][dd] * wv;
    }
    for (int tk = 0; tk < ntk; ++tk)
        Hpart[((size_t)blockIdx.y * CAP + (t0 + tk)) * FF + f] = acc[tk];
}

// resolve flagged tokens: exact fp32 logit (fixed kc order -> deterministic)
__global__ void fixres2(const float* __restrict__ sx, const float* __restrict__ spb,
                        const float* __restrict__ Hpart, const float* __restrict__ qv,
                        const int* __restrict__ flags, const int* __restrict__ cnt,
                        float* __restrict__ w, int* __restrict__ mi)
{
    const int nb = min(*cnt, CAP);
    const int i  = blockIdx.x * 4 + (threadIdx.x >> 6);
    const int ln = threadIdx.x & 63;
    if (i >= nb) return;                       // wave-uniform
    float s = 0.f;
    for (int f = ln; f < FF; f += 64) {
        const float h = Hpart[(size_t)(0 * CAP + i) * FF + f]
                      + Hpart[(size_t)(1 * CAP + i) * FF + f]
                      + Hpart[(size_t)(2 * CAP + i) * FF + f]
                      + Hpart[(size_t)(3 * CAP + i) * FF + f];
        s += fmaxf(h, 0.f) * qv[f];
    }
    #pragma unroll
    for (int off = 32; off > 0; off >>= 1) s += __shfl_xor(s, off, 64);
    if (ln == 0) {
        const int t = flags[i];
        const float logit = sx[t] + s + spb[0];
        const float sg = 1.f / (1.f + expf(-logit));
        w[t]  = sg;
        mi[t] = (sg >= 0.5f) ? 1 : 0;
    }
}

__global__ void scan_kernel(const int* __restrict__ mi, const int* __restrict__ cu,
                            int* __restrict__ ecs, int* __restrict__ meta)
{
    __shared__ int sums[256];
    const int tid  = threadIdx.x;
    const int base = tid * 64;
    int s = 0;
    for (int i = 0; i < 64; ++i) s += mi[base + i];
    sums[tid] = s;
    __syncthreads();
    for (int off = 1; off < 256; off <<= 1) {
        int v = (tid >= off) ? sums[tid - off] : 0;
        __syncthreads();
        sums[tid] += v;
        __syncthreads();
    }
    int run = (tid == 0) ? 0 : sums[tid - 1];
    for (int i = 0; i < 64; ++i) { ecs[base + i] = run; run += mi[base + i]; }
    if (tid == 255) meta[0] = sums[255];
    if (tid < 4) {
        const int idx = cu[tid];
        const int tc = idx >> 6, rem = idx & 63;
        int e = (tc == 0) ? 0 : sums[tc - 1];
        for (int i = 0; i < rem; ++i) e += mi[tc * 64 + i];
        meta[1 + tid] = e;
    }
}

__global__ void pack_kernel(const float* __restrict__ enc, const float* __restrict__ w,
                            const int* __restrict__ mi, const int* __restrict__ ecs,
                            const int* __restrict__ cu, const int* __restrict__ meta,
                            const float* __restrict__ pos_emb,
                            float* __restrict__ Pf, bf16* __restrict__ Pb)
{
    const int t    = blockIdx.x * 4 + (threadIdx.x >> 6);
    const int lane = threadIdx.x & 63;
    if (!mi[t]) return;
    const int e = ecs[t];
    int seg = 0;
    #pragma unroll
    for (int ss = 1; ss < 4; ++ss) if (t >= cu[ss]) seg = ss;
    const int np = e - meta[1 + seg];
    const float wt = w[t];
    const float4* src = (const float4*)(enc + (size_t)t * DD);
    const float4* pe  = (const float4*)(pos_emb + (size_t)np * DD);
    float4* dstf = (float4*)(Pf + (size_t)e * DD);
    bf16*   dstb = Pb + (size_t)e * DD;
    for (int c = lane; c < DD / 4; c += 64) {
        float4 v = src[c], p = pe[c];
        v.x = v.x * wt + p.x; v.y = v.y * wt + p.y;
        v.z = v.z * wt + p.z; v.w = v.w * wt + p.w;
        dstf[c] = v;
        dstb[c * 4 + 0] = __float2bfloat16(v.x);
        dstb[c * 4 + 1] = __float2bfloat16(v.y);
        dstb[c * 4 + 2] = __float2bfloat16(v.z);
        dstb[c * 4 + 3] = __float2bfloat16(v.w);
    }
}

__global__ void combine_kernel(float* __restrict__ ENC, const float* __restrict__ BBf,
                               const int* __restrict__ mi, const int* __restrict__ ecs,
                               bf16* __restrict__ Cb)
{
    const int t    = blockIdx.x * 4 + (threadIdx.x >> 6);
    const int lane = threadIdx.x & 63;
    const bool kept = mi[t] != 0;
    const float4* src = kept ? (const float4*)(BBf + (size_t)ecs[t] * DD)
                             : (const float4*)(ENC + (size_t)t * DD);
    float4* dstf = (float4*)(ENC + (size_t)t * DD);
    bf16*   dstb = Cb + (size_t)t * DD;
    for (int c = lane; c < DD / 4; c += 64) {
        const float4 v = src[c];
        if (kept) dstf[c] = v;
        dstb[c * 4 + 0] = __float2bfloat16(v.x);
        dstb[c * 4 + 1] = __float2bfloat16(v.y);
        dstb[c * 4 + 2] = __float2bfloat16(v.z);
        dstb[c * 4 + 3] = __float2bfloat16(v.w);
    }
}

// ---------------------------------------------------------------------------
extern "C" void kernel_launch(void* const* d_in, const int* in_sizes, int n_in,
                              void* d_out, int out_size, void* d_ws, size_t ws_size,
                              hipStream_t stream)
{
    (void)in_sizes; (void)n_in; (void)out_size; (void)ws_size;
    const float* x   = (const float*)d_in[0];
    const float* ew1 = (const float*)d_in[1];
    const float* ew2 = (const float*)d_in[2];
    const float* bw1 = (const float*)d_in[3];
    const float* bw2 = (const float*)d_in[4];
    const float* dw1 = (const float*)d_in[5];
    const float* dw2 = (const float*)d_in[6];
    const float* spw = (const float*)d_in[7];
    const float* spb = (const float*)d_in[8];
    const float* pem = (const float*)d_in[9];
    const float* lmh = (const float*)d_in[10];
    const int*   cu  = (const int*)d_in[11];
    float* out = (float*)d_out;

    (void)hipFuncSetAttribute((const void*)mgemm8<1, true, false, false, true>,
                              hipFuncAttributeMaxDynamicSharedMemorySize, 131072);
    (void)hipFuncSetAttribute((const void*)mgemm8<2, false, true, false, false>,
                              hipFuncAttributeMaxDynamicSharedMemorySize, 131072);
    (void)hipFuncSetAttribute((const void*)mgemm8<1, true, false, true, false>,
                              hipFuncAttributeMaxDynamicSharedMemorySize, 131072);
    (void)hipFuncSetAttribute((const void*)mgemm8<2, false, true, true, false>,
                              hipFuncAttributeMaxDynamicSharedMemorySize, 131072);
    (void)hipFuncSetAttribute((const void*)mgemm8<1, true, false, false, false>,
                              hipFuncAttributeMaxDynamicSharedMemorySize, 131072);
    (void)hipFuncSetAttribute((const void*)mgemm8<2, true, false, false, false>,
                              hipFuncAttributeMaxDynamicSharedMemorySize, 131072);
    (void)hipFuncSetAttribute((const void*)mgemm8<0, false, true, false, false>,
                              hipFuncAttributeMaxDynamicSharedMemorySize, 131072);

    // ---- workspace carve (~305 MB; Hpart aliases Pf) ----
    char* w = (char*)d_ws;
    auto alloc = [&](size_t bytes) { char* p = w; w += bytes; return p; };
    bf16* ew1T = (bf16*)alloc((size_t)FF * DD * 2);
    bf16* ew2T = (bf16*)alloc((size_t)DD * FF * 2);
    bf16* bw1T = (bf16*)alloc((size_t)FF * DD * 2);
    bf16* bw2T = (bf16*)alloc((size_t)DD * FF * 2);
    bf16* dw1T = (bf16*)alloc((size_t)FF * DD * 2);
    bf16* dw2T = (bf16*)alloc((size_t)DD * FF * 2);
    bf16* lmhT = (bf16*)alloc((size_t)VV * DD * 2);
    float* qv  = (float*)alloc((size_t)FF * 4);
    float* GP  = (float*)alloc((size_t)32 * TT * 4);
    float* WG  = (float*)alloc((size_t)TT * 4);
    int*  MI   = (int*)alloc((size_t)TT * 4);
    int*  ECS  = (int*)alloc((size_t)TT * 4);
    int*  META = (int*)alloc(64);
    float* SX  = (float*)alloc((size_t)TT * 4);
    int*  FLAGS= (int*)alloc((size_t)CAP * 4);
    int*  CNT  = (int*)alloc(64);
    bf16* Xb   = (bf16*)alloc((size_t)TT * DD * 2);   // enc1 A; reused as Cb
    bf16* Hb   = (bf16*)alloc((size_t)TT * FF * 2);   // hidden (all MLPs)
    float* ENC = (float*)alloc((size_t)TT * DD * 4);  // later: Cf (in place)
    float* Pf  = (float*)alloc((size_t)TT * DD * 4);  // later: BBf (in place)
    bf16* Pb   = (bf16*)alloc((size_t)TT * DD * 2);   // reused as DECb
    bf16* Cb   = Xb;
    bf16* DECb = Pb;
    float* Hpart = Pf;   // alias: fixup partials dead before pack writes Pf

    const dim3 blk(256);
    const dim3 blk8(512);

    (void)hipMemsetAsync(CNT, 0, 4, stream);

    // ---- prep ----
    castx2<<<TT / 4, blk, 0, stream>>>(x, spw, Xb, SX);
    wtrans_all<<<16384, blk, 0, stream>>>(ew1, ew2, bw1, bw2, dw1, dw2, lmh,
                                          ew1T, ew2T, bw1T, bw2T, dw1T, dw2T, lmhT);
    qvec<<<FF / 4, blk, 0, stream>>>(ew2, spw, qv);

    // ---- encoder GEMM1: plain bf16 8-phase + fused gate partials ----
    mgemm8<1, true, false, false, true><<<dim3(FF / 256, TT / 256), blk8, 131072, stream>>>(
        Xb, ew1T, nullptr, Hb, nullptr, GP, qv, TT, FF, DD, nullptr);

    // ---- gate (approx) + exact borderline fixup + scan ----
    gate2<<<TT / 256, blk, 0, stream>>>(SX, spb, GP, WG, MI, FLAGS, CNT);
    fixh<<<dim3(FF / 256, 4, CAP / 32), blk, 0, stream>>>(x, ew1, FLAGS, CNT, Hpart);
    fixres2<<<CAP / 4, blk, 0, stream>>>(SX, spb, Hpart, qv, FLAGS, CNT, WG, MI);
    scan_kernel<<<1, blk, 0, stream>>>(MI, cu, ECS, META);

    // ---- encoder GEMM2: ENC = Hb @ ew2 + x (fp32 out) ----
    mgemm8<2, false, true, false, false><<<dim3(DD / 256, TT / 256), blk8, 131072, stream>>>(
        Hb, ew2T, x, nullptr, ENC, nullptr, nullptr, TT, DD, FF, nullptr);

    // ---- pack kept rows ----
    pack_kernel<<<TT / 4, blk, 0, stream>>>(ENC, WG, MI, ECS, cu, META, pem, Pf, Pb);

    // ---- backbone (rowlim) ----
    mgemm8<1, true, false, true, false><<<dim3(FF / 256, TT / 256), blk8, 131072, stream>>>(
        Pb, bw1T, nullptr, Hb, nullptr, nullptr, nullptr, TT, FF, DD, META);
    mgemm8<2, false, true, true, false><<<dim3(DD / 256, TT / 256), blk8, 131072, stream>>>(
        Hb, bw2T, Pf, nullptr, Pf, nullptr, nullptr, TT, DD, FF, META);

    // ---- scatter-combine (Cf = ENC in place, Cb bf16) ----
    combine_kernel<<<TT / 4, blk, 0, stream>>>(ENC, Pf, MI, ECS, Cb);

    // ---- decoder ----
    mgemm8<1, true, false, false, false><<<dim3(FF / 256, TT / 256), blk8, 131072, stream>>>(
        Cb, dw1T, nullptr, Hb, nullptr, nullptr, nullptr, TT, FF, DD, nullptr);
    mgemm8<2, true, false, false, false><<<dim3(DD / 256, TT / 256), blk8, 131072, stream>>>(
        Hb, dw2T, ENC, DECb, nullptr, nullptr, nullptr, TT, DD, FF, nullptr);

    // ---- lm head ----
    mgemm8<0, false, true, false, false><<<dim3(VV / 256, TT / 256), blk8, 131072, stream>>>(
        DECb, lmhT, nullptr, nullptr, out, nullptr, nullptr, TT, VV, DD, nullptr);
}

// Round 8
// 732.914 us; speedup vs baseline: 43.9037x; 1.0447x over previous
//
#include <hip/hip_runtime.h>
#include <hip/hip_bf16.h>
#include <math.h>
#include <string.h>

static constexpr int TT = 16384;
static constexpr int DD = 1024;
static constexpr int FF = 2048;
static constexpr int VV = 4096;
static constexpr int CAP = 1024;       // borderline-token capacity (exp ~190)
#define TAU 0.02f                      // |logit| flag threshold

using bf16 = __hip_bfloat16;
typedef __attribute__((ext_vector_type(8))) short bf16x8;
typedef __attribute__((ext_vector_type(4))) float f32x4;

__device__ inline void gload16(const void* g, void* l) {
    __builtin_amdgcn_global_load_lds(
        (const __attribute__((address_space(1))) void*)g,
        (__attribute__((address_space(3))) void*)l, 16, 0, 0);
}
__device__ inline float b2f(short s) {
    unsigned u = (unsigned)(unsigned short)s << 16;
    float f; __builtin_memcpy(&f, &u, 4); return f;
}
__device__ inline short f2b(float f) {
    bf16 h = __float2bfloat16(f);
    unsigned short us; __builtin_memcpy(&us, &h, 2); return (short)us;
}

// ===========================================================================
// 8-phase 256x256 MFMA GEMM (round-4 verified schedule) + XCD swizzle (T1).
// A [M,K] bf16 row-major, BT [N,K] bf16 (B^T). 512 thr = 8 waves (2M x 4N),
// per-wave out 128x64 (8 mf x 4 nf frags of 16x16x32). BK=64, 2 K-tiles/iter.
// LDS 128 KiB: buf{0,1} x {A[256][64] | B[256][64]}. Stage stream: half j,
// tile=j>>2, part order {B h0, B h1, A h0, A h1}; vmcnt(6) at phases A3/B3.
// EPI: 0 none, 1 relu, 2 +Xf32, 3 +Xbf16.
// ===========================================================================
template<int EPI, bool WB16, bool WF32, bool ROWLIM, bool GPART>
__global__ __launch_bounds__(512, 2)
void mgemm8(const bf16* __restrict__ A, const bf16* __restrict__ BT,
            const float* __restrict__ Xf, const bf16* __restrict__ Xh,
            bf16* __restrict__ Ob, float* __restrict__ Of,
            float* __restrict__ gpart, const float* __restrict__ qv,
            int M, int N, int K, const int* __restrict__ rowlim)
{
    // bijective XCD swizzle (nwg % 8 == 0 for every launch here)
    const int gx = gridDim.x;
    const int lin = blockIdx.x + blockIdx.y * gx;
    const int nwg = gx * gridDim.y;
    const int wg = (lin & 7) * (nwg >> 3) + (lin >> 3);
    const int bx = wg % gx, by = wg / gx;

    if constexpr (ROWLIM) { if (by * 256 >= *rowlim) return; }
    const int m0 = by * 256, n0 = bx * 256;

    extern __shared__ char smem[];   // 2 bufs x (A 32K | B 32K) = 128 KiB

    const int tid = threadIdx.x;
    const int wv = tid >> 6, ln = tid & 63;
    const int wm = wv >> 2, wn = wv & 3;
    const int lr = ln & 15, lk = ln >> 4;
    const int swz = (lr & 7) << 4;

    const bf16* Ag = A  + (size_t)m0 * K;
    const bf16* Bg = BT + (size_t)n0 * K;

    const int NT = K >> 6;
    const int NI = NT >> 1;

    const int aoff0 = (wm * 128 + lr) * 128;
    const int boff0 = 32768 + (wn * 64 + lr) * 128;
    const int cb0 = (lk * 16) ^ swz;
    const int cb1 = (64 + lk * 16) ^ swz;

    auto STAGE = [&](const bf16* g, int h, int kt, int buf, int op) {
        const int r = ln >> 3;
        const int c = ((ln & 7) ^ r) * 8;
        const bf16* s = g + (size_t)(h * 128 + wv * 16 + r) * K + kt * 64 + c;
        char* d = smem + buf * 65536 + op * 32768 + h * 16384 + wv * 2048;
        gload16(s, d);
        gload16(s + (size_t)8 * K, d + 1024);
    };
    auto stage_j = [&](int j) {
        const int tile = j >> 2;
        if (tile >= NT) return;
        const int part = j & 3;
        const int buf = tile & 1;
        if (part < 2) STAGE(Bg, part, tile, buf, 1);
        else          STAGE(Ag, part - 2, tile, buf, 0);
    };

    bf16x8 afr[2][2], bfr[4][2];
    f32x4 acc[8][4];
    #pragma unroll
    for (int m = 0; m < 8; ++m)
        #pragma unroll
        for (int n = 0; n < 4; ++n) acc[m][n] = (f32x4){0.f, 0.f, 0.f, 0.f};

#define DS_A(BUF, Q) do {                                                     \
    const char* _p = smem + (BUF) * 65536 + aoff0 + (Q) * 4096;               \
    afr[0][0] = *(const bf16x8*)(_p + cb0);                                   \
    afr[0][1] = *(const bf16x8*)(_p + cb1);                                   \
    afr[1][0] = *(const bf16x8*)(_p + 2048 + cb0);                            \
    afr[1][1] = *(const bf16x8*)(_p + 2048 + cb1);                            \
} while (0)

#define DS_B(BUF) do {                                                        \
    const char* _p = smem + (BUF) * 65536 + boff0;                            \
    _Pragma("unroll")                                                         \
    for (int nf = 0; nf < 4; ++nf) {                                          \
        bfr[nf][0] = *(const bf16x8*)(_p + nf * 2048 + cb0);                  \
        bfr[nf][1] = *(const bf16x8*)(_p + nf * 2048 + cb1);                  \
    }                                                                         \
} while (0)

#define MFMAQ(Q) do {                                                         \
    __builtin_amdgcn_s_setprio(1);                                            \
    _Pragma("unroll")                                                         \
    for (int m2 = 0; m2 < 2; ++m2)                                            \
        _Pragma("unroll")                                                     \
        for (int nf = 0; nf < 4; ++nf) {                                      \
            acc[(Q) * 2 + m2][nf] = __builtin_amdgcn_mfma_f32_16x16x32_bf16(  \
                afr[m2][0], bfr[nf][0], acc[(Q) * 2 + m2][nf], 0, 0, 0);      \
            acc[(Q) * 2 + m2][nf] = __builtin_amdgcn_mfma_f32_16x16x32_bf16(  \
                afr[m2][1], bfr[nf][1], acc[(Q) * 2 + m2][nf], 0, 0, 0);      \
        }                                                                     \
    __builtin_amdgcn_s_setprio(0);                                            \
} while (0)

// W: 0 = no wait, 1 = vmcnt(6), 2 = vmcnt(0)
#define PHASE(Q, BUF, DOB, J, W)                                              \
    {                                                                         \
        DS_A(BUF, Q);                                                         \
        if (DOB) DS_B(BUF);                                                   \
        stage_j(J);                                                           \
        if ((W) == 1)      asm volatile("s_waitcnt vmcnt(6)" ::: "memory");   \
        else if ((W) == 2) asm volatile("s_waitcnt vmcnt(0)" ::: "memory");   \
        __builtin_amdgcn_sched_barrier(0);                                    \
        __builtin_amdgcn_s_barrier();                                         \
        MFMAQ(Q);                                                             \
        __builtin_amdgcn_s_barrier();                                         \
    }

    STAGE(Bg, 0, 0, 0, 1); STAGE(Bg, 1, 0, 0, 1);
    STAGE(Ag, 0, 0, 0, 0); STAGE(Ag, 1, 0, 0, 0);
    asm volatile("s_waitcnt vmcnt(4)" ::: "memory");
    STAGE(Bg, 0, 1, 1, 1); STAGE(Bg, 1, 1, 1, 1);
    STAGE(Ag, 0, 1, 1, 0);
    asm volatile("s_waitcnt vmcnt(6)" ::: "memory");
    __builtin_amdgcn_sched_barrier(0);
    __builtin_amdgcn_s_barrier();

    for (int i = 0; i < NI; ++i) {
        const int jb = 7 + 8 * i;
        const bool last = (i + 1 == NI);
        PHASE(0, 0, true,  jb + 0, 0);
        PHASE(1, 0, false, jb + 1, 0);
        PHASE(2, 0, false, jb + 2, 0);
        PHASE(3, 0, false, jb + 3, last ? 2 : 1);
        PHASE(0, 1, true,  jb + 4, 0);
        PHASE(1, 1, false, jb + 5, 0);
        PHASE(2, 1, false, jb + 6, 0);
        PHASE(3, 1, false, jb + 7, last ? 0 : 1);
    }

#undef PHASE
#undef MFMAQ
#undef DS_B
#undef DS_A

    if constexpr (GPART) {
        float qvv[4];
        #pragma unroll
        for (int nf = 0; nf < 4; ++nf) qvv[nf] = qv[n0 + wn * 64 + nf * 16 + lr];
        #pragma unroll
        for (int mf = 0; mf < 8; ++mf)
            #pragma unroll
            for (int rr = 0; rr < 4; ++rr) {
                float s = 0.f;
                #pragma unroll
                for (int nf = 0; nf < 4; ++nf) s += fmaxf(acc[mf][nf][rr], 0.f) * qvv[nf];
                s += __shfl_xor(s, 1, 64); s += __shfl_xor(s, 2, 64);
                s += __shfl_xor(s, 4, 64); s += __shfl_xor(s, 8, 64);
                if (lr == 0)
                    gpart[(size_t)(bx * 4 + wn) * M +
                          (m0 + wm * 128 + mf * 16 + lk * 4 + rr)] = s;
            }
    }

    #pragma unroll
    for (int mf = 0; mf < 8; ++mf)
        #pragma unroll
        for (int nf = 0; nf < 4; ++nf)
            #pragma unroll
            for (int rr = 0; rr < 4; ++rr) {
                const int row = m0 + wm * 128 + mf * 16 + lk * 4 + rr;
                const int col = n0 + wn * 64 + nf * 16 + lr;
                float v = acc[mf][nf][rr];
                if constexpr (EPI == 1) v = fmaxf(v, 0.f);
                if constexpr (EPI == 2) v += Xf[(size_t)row * N + col];
                if constexpr (EPI == 3) v += __bfloat162float(Xh[(size_t)row * N + col]);
                if constexpr (WB16) Ob[(size_t)row * N + col] = __float2bfloat16(v);
                if constexpr (WF32) Of[(size_t)row * N + col] = v;
            }
}

// ---------------------------------------------------------------------------
// fused weight transposes: 6x [DD<->FF] + lmh [DD][VV] -> bf16 B^T layouts
// ---------------------------------------------------------------------------
__global__ void wtrans_all(const float* __restrict__ e1, const float* __restrict__ e2,
                           const float* __restrict__ b1, const float* __restrict__ b2,
                           const float* __restrict__ d1, const float* __restrict__ d2,
                           const float* __restrict__ lm,
                           bf16* __restrict__ e1T, bf16* __restrict__ e2T,
                           bf16* __restrict__ b1T, bf16* __restrict__ b2T,
                           bf16* __restrict__ d1T, bf16* __restrict__ d2T,
                           bf16* __restrict__ lmT)
{
    int bid = blockIdx.x;
    const float* W; bf16* T; int R, C;
    if (bid < 12288) {
        const int m = bid >> 11;
        bid &= 2047;
        R = (m & 1) ? FF : DD;
        C = (m & 1) ? DD : FF;
        switch (m) {
            case 0:  W = e1; T = e1T; break;
            case 1:  W = e2; T = e2T; break;
            case 2:  W = b1; T = b1T; break;
            case 3:  W = b2; T = b2T; break;
            case 4:  W = d1; T = d1T; break;
            default: W = d2; T = d2T; break;
        }
    } else {
        bid -= 12288; W = lm; T = lmT; R = DD; C = VV;
    }
    const int tc = C >> 5;
    const int cb = (bid % tc) * 32, rb = (bid / tc) * 32;

    __shared__ float tile[32][33];
    const int tx = threadIdx.x & 31, ty = threadIdx.x >> 5;
    #pragma unroll
    for (int i = 0; i < 32; i += 8)
        tile[ty + i][tx] = W[(size_t)(rb + ty + i) * C + cb + tx];
    __syncthreads();
    #pragma unroll
    for (int i = 0; i < 32; i += 8)
        T[(size_t)(cb + ty + i) * R + rb + tx] = __float2bfloat16(tile[tx][ty + i]);
}

// x -> bf16 cast + fused row-dot sx[t] = x[t]·spw  (one wave per token)
__global__ void castx2(const float* __restrict__ x, const float* __restrict__ spw,
                       bf16* __restrict__ xb, float* __restrict__ sx)
{
    const int t  = blockIdx.x * 4 + (threadIdx.x >> 6);
    const int ln = threadIdx.x & 63;
    const float4* row = (const float4*)(x + (size_t)t * DD);
    const float4* sp4 = (const float4*)spw;
    bf16* dst = xb + (size_t)t * DD;
    float s = 0.f;
    #pragma unroll
    for (int q = 0; q < 4; ++q) {
        const int c = q * 64 + ln;
        const float4 v = row[c], p = sp4[c];
        s += v.x * p.x + v.y * p.y + v.z * p.z + v.w * p.w;
        dst[c * 4 + 0] = __float2bfloat16(v.x);
        dst[c * 4 + 1] = __float2bfloat16(v.y);
        dst[c * 4 + 2] = __float2bfloat16(v.z);
        dst[c * 4 + 3] = __float2bfloat16(v.w);
    }
    #pragma unroll
    for (int off = 32; off > 0; off >>= 1) s += __shfl_xor(s, off, 64);
    if (ln == 0) sx[t] = s;
}

// q[f] = sum_d w2[f][d] * sp[d]
__global__ void qvec(const float* __restrict__ w2, const float* __restrict__ sp,
                     float* __restrict__ q)
{
    const int f  = blockIdx.x * 4 + (threadIdx.x >> 6);
    const int ln = threadIdx.x & 63;
    float s = 0.f;
    const float* row = w2 + (size_t)f * DD;
    for (int k = ln; k < DD; k += 64) s += row[k] * sp[k];
    #pragma unroll
    for (int off = 32; off > 0; off >>= 1) s += __shfl_xor(s, off, 64);
    if (ln == 0) q[f] = s;
}

// gate: logit~ = sx + Σ gpart + b ; flag |logit~| < TAU (thread per token)
__global__ void gate2(const float* __restrict__ sx, const float* __restrict__ spb,
                      const float* __restrict__ gpart, float* __restrict__ w,
                      int* __restrict__ mi, int* __restrict__ flags,
                      int* __restrict__ cnt)
{
    const int t = blockIdx.x * 256 + threadIdx.x;
    float s = sx[t] + spb[0];
    #pragma unroll
    for (int j = 0; j < 32; ++j) s += gpart[(size_t)j * TT + t];
    const float sg = 1.f / (1.f + expf(-s));
    w[t]  = sg;
    mi[t] = (sg >= 0.5f) ? 1 : 0;
    if (fabsf(s) < TAU) {
        const int i = atomicAdd(cnt, 1);
        if (i < CAP) flags[i] = t;
    }
}

// split-K exact partial dots for flagged tokens
__global__ __launch_bounds__(256)
void fixh(const float* __restrict__ x, const float* __restrict__ w1,
          const int* __restrict__ flags, const int* __restrict__ cnt,
          float* __restrict__ Hpart)
{
    const int nb = min(*cnt, CAP);
    const int t0 = blockIdx.z * 32;
    if (t0 >= nb) return;
    const int ntk = min(32, nb - t0);
    const int f  = blockIdx.x * 256 + threadIdx.x;
    const int d0 = blockIdx.y * 256;

    __shared__ float xs[32][256];
    for (int i = threadIdx.x; i < 32 * 64; i += 256) {
        const int tk = i >> 6, dq = i & 63;
        float4 v = (tk < ntk)
            ? *(const float4*)&x[(size_t)flags[t0 + tk] * DD + d0 + dq * 4]
            : make_float4(0.f, 0.f, 0.f, 0.f);
        *(float4*)&xs[tk][dq * 4] = v;
    }
    __syncthreads();

    float acc[32];
    #pragma unroll
    for (int tk = 0; tk < 32; ++tk) acc[tk] = 0.f;
    for (int dd = 0; dd < 256; ++dd) {
        const float wv = w1[(size_t)(d0 + dd) * FF + f];
        #pragma unroll
        for (int tk = 0; tk < 32; ++tk) acc[tk] += xs[tk][dd] * wv;
    }
    for (int tk = 0; tk < ntk; ++tk)
        Hpart[((size_t)blockIdx.y * CAP + (t0 + tk)) * FF + f] = acc[tk];
}

// resolve flagged tokens: exact fp32 logit (fixed kc order -> deterministic)
__global__ void fixres2(const float* __restrict__ sx, const float* __restrict__ spb,
                        const float* __restrict__ Hpart, const float* __restrict__ qv,
                        const int* __restrict__ flags, const int* __restrict__ cnt,
                        float* __restrict__ w, int* __restrict__ mi)
{
    const int nb = min(*cnt, CAP);
    const int i  = blockIdx.x * 4 + (threadIdx.x >> 6);
    const int ln = threadIdx.x & 63;
    if (i >= nb) return;                       // wave-uniform
    float s = 0.f;
    for (int f = ln; f < FF; f += 64) {
        const float h = Hpart[(size_t)(0 * CAP + i) * FF + f]
                      + Hpart[(size_t)(1 * CAP + i) * FF + f]
                      + Hpart[(size_t)(2 * CAP + i) * FF + f]
                      + Hpart[(size_t)(3 * CAP + i) * FF + f];
        s += fmaxf(h, 0.f) * qv[f];
    }
    #pragma unroll
    for (int off = 32; off > 0; off >>= 1) s += __shfl_xor(s, off, 64);
    if (ln == 0) {
        const int t = flags[i];
        const float logit = sx[t] + s + spb[0];
        const float sg = 1.f / (1.f + expf(-logit));
        w[t]  = sg;
        mi[t] = (sg >= 0.5f) ? 1 : 0;
    }
}

__global__ void scan_kernel(const int* __restrict__ mi, const int* __restrict__ cu,
                            int* __restrict__ ecs, int* __restrict__ meta)
{
    __shared__ int sums[256];
    const int tid  = threadIdx.x;
    const int base = tid * 64;
    int s = 0;
    for (int i = 0; i < 64; ++i) s += mi[base + i];
    sums[tid] = s;
    __syncthreads();
    for (int off = 1; off < 256; off <<= 1) {
        int v = (tid >= off) ? sums[tid - off] : 0;
        __syncthreads();
        sums[tid] += v;
        __syncthreads();
    }
    int run = (tid == 0) ? 0 : sums[tid - 1];
    for (int i = 0; i < 64; ++i) { ecs[base + i] = run; run += mi[base + i]; }
    if (tid == 255) meta[0] = sums[255];
    if (tid < 4) {
        const int idx = cu[tid];
        const int tc = idx >> 6, rem = idx & 63;
        int e = (tc == 0) ? 0 : sums[tc - 1];
        for (int i = 0; i < rem; ++i) e += mi[tc * 64 + i];
        meta[1 + tid] = e;
    }
}

// pack: Pb[e] = bf16(ENCb[t]*w[t] + pos_emb[rank])   (bf16 in/out)
__global__ void pack_kernel(const bf16* __restrict__ enc, const float* __restrict__ w,
                            const int* __restrict__ mi, const int* __restrict__ ecs,
                            const int* __restrict__ cu, const int* __restrict__ meta,
                            const float* __restrict__ pos_emb, bf16* __restrict__ Pb)
{
    const int t    = blockIdx.x * 4 + (threadIdx.x >> 6);
    const int lane = threadIdx.x & 63;
    if (!mi[t]) return;
    const int e = ecs[t];
    int seg = 0;
    #pragma unroll
    for (int ss = 1; ss < 4; ++ss) if (t >= cu[ss]) seg = ss;
    const int np = e - meta[1 + seg];
    const float wt = w[t];
    const bf16x8* src = (const bf16x8*)(enc + (size_t)t * DD);
    const float4* pe  = (const float4*)(pos_emb + (size_t)np * DD);
    bf16x8* dst = (bf16x8*)(Pb + (size_t)e * DD);
    #pragma unroll
    for (int q = 0; q < 2; ++q) {
        const int c = q * 64 + lane;        // 128 chunks of 8 bf16
        const bf16x8 v = src[c];
        const float4 p0 = pe[c * 2], p1 = pe[c * 2 + 1];
        bf16x8 r;
        r[0] = f2b(b2f(v[0]) * wt + p0.x);
        r[1] = f2b(b2f(v[1]) * wt + p0.y);
        r[2] = f2b(b2f(v[2]) * wt + p0.z);
        r[3] = f2b(b2f(v[3]) * wt + p0.w);
        r[4] = f2b(b2f(v[4]) * wt + p1.x);
        r[5] = f2b(b2f(v[5]) * wt + p1.y);
        r[6] = f2b(b2f(v[6]) * wt + p1.z);
        r[7] = f2b(b2f(v[7]) * wt + p1.w);
        dst[c] = r;
    }
}

// combine: Cb[t] = kept ? BBb[ecs[t]] : ENCb[t]   (pure bf16 row copy)
__global__ void combine_kernel(const bf16* __restrict__ ENCb, const bf16* __restrict__ BBb,
                               const int* __restrict__ mi, const int* __restrict__ ecs,
                               bf16* __restrict__ Cb)
{
    const int t    = blockIdx.x * 4 + (threadIdx.x >> 6);
    const int lane = threadIdx.x & 63;
    const bool kept = mi[t] != 0;
    const int4* src = kept ? (const int4*)(BBb + (size_t)ecs[t] * DD)
                           : (const int4*)(ENCb + (size_t)t * DD);
    int4* dst = (int4*)(Cb + (size_t)t * DD);
    #pragma unroll
    for (int q = 0; q < 2; ++q) dst[q * 64 + lane] = src[q * 64 + lane];
}

// ---------------------------------------------------------------------------
extern "C" void kernel_launch(void* const* d_in, const int* in_sizes, int n_in,
                              void* d_out, int out_size, void* d_ws, size_t ws_size,
                              hipStream_t stream)
{
    (void)in_sizes; (void)n_in; (void)out_size; (void)ws_size;
    const float* x   = (const float*)d_in[0];
    const float* ew1 = (const float*)d_in[1];
    const float* ew2 = (const float*)d_in[2];
    const float* bw1 = (const float*)d_in[3];
    const float* bw2 = (const float*)d_in[4];
    const float* dw1 = (const float*)d_in[5];
    const float* dw2 = (const float*)d_in[6];
    const float* spw = (const float*)d_in[7];
    const float* spb = (const float*)d_in[8];
    const float* pem = (const float*)d_in[9];
    const float* lmh = (const float*)d_in[10];
    const int*   cu  = (const int*)d_in[11];
    float* out = (float*)d_out;

    (void)hipFuncSetAttribute((const void*)mgemm8<1, true, false, false, true>,
                              hipFuncAttributeMaxDynamicSharedMemorySize, 131072);
    (void)hipFuncSetAttribute((const void*)mgemm8<3, true, false, false, false>,
                              hipFuncAttributeMaxDynamicSharedMemorySize, 131072);
    (void)hipFuncSetAttribute((const void*)mgemm8<1, true, false, true, false>,
                              hipFuncAttributeMaxDynamicSharedMemorySize, 131072);
    (void)hipFuncSetAttribute((const void*)mgemm8<3, true, false, true, false>,
                              hipFuncAttributeMaxDynamicSharedMemorySize, 131072);
    (void)hipFuncSetAttribute((const void*)mgemm8<1, true, false, false, false>,
                              hipFuncAttributeMaxDynamicSharedMemorySize, 131072);
    (void)hipFuncSetAttribute((const void*)mgemm8<0, false, true, false, false>,
                              hipFuncAttributeMaxDynamicSharedMemorySize, 131072);

    // ---- workspace carve (~260 MB; Hpart aliases BBb) ----
    char* w = (char*)d_ws;
    auto alloc = [&](size_t bytes) { char* p = w; w += bytes; return p; };
    bf16* ew1T = (bf16*)alloc((size_t)FF * DD * 2);
    bf16* ew2T = (bf16*)alloc((size_t)DD * FF * 2);
    bf16* bw1T = (bf16*)alloc((size_t)FF * DD * 2);
    bf16* bw2T = (bf16*)alloc((size_t)DD * FF * 2);
    bf16* dw1T = (bf16*)alloc((size_t)FF * DD * 2);
    bf16* dw2T = (bf16*)alloc((size_t)DD * FF * 2);
    bf16* lmhT = (bf16*)alloc((size_t)VV * DD * 2);
    float* qv  = (float*)alloc((size_t)FF * 4);
    float* GP  = (float*)alloc((size_t)32 * TT * 4);
    float* WG  = (float*)alloc((size_t)TT * 4);
    int*  MI   = (int*)alloc((size_t)TT * 4);
    int*  ECS  = (int*)alloc((size_t)TT * 4);
    int*  META = (int*)alloc(64);
    float* SX  = (float*)alloc((size_t)TT * 4);
    int*  FLAGS= (int*)alloc((size_t)CAP * 4);
    int*  CNT  = (int*)alloc(64);
    bf16* Xb   = (bf16*)alloc((size_t)TT * DD * 2);   // x bf16; reused as Cb
    bf16* Hb   = (bf16*)alloc((size_t)TT * FF * 2);   // hidden (all MLPs)
    bf16* ENCb = (bf16*)alloc((size_t)TT * DD * 2);
    bf16* Pb   = (bf16*)alloc((size_t)TT * DD * 2);   // reused as DECb
    bf16* BBb  = (bf16*)alloc((size_t)TT * DD * 2);
    bf16* Cb   = Xb;           // Xb dead after enc2 residual
    bf16* DECb = Pb;           // Pb dead after bb2
    float* Hpart = (float*)BBb; // 4*CAP*FF*4 = 32 MB, dead before bb2 writes BBb

    const dim3 blk(256);
    const dim3 blk8(512);

    (void)hipMemsetAsync(CNT, 0, 4, stream);

    // ---- prep ----
    castx2<<<TT / 4, blk, 0, stream>>>(x, spw, Xb, SX);
    wtrans_all<<<16384, blk, 0, stream>>>(ew1, ew2, bw1, bw2, dw1, dw2, lmh,
                                          ew1T, ew2T, bw1T, bw2T, dw1T, dw2T, lmhT);
    qvec<<<FF / 4, blk, 0, stream>>>(ew2, spw, qv);

    // ---- encoder GEMM1: bf16 8-phase + fused gate partials ----
    mgemm8<1, true, false, false, true><<<dim3(FF / 256, TT / 256), blk8, 131072, stream>>>(
        Xb, ew1T, nullptr, nullptr, Hb, nullptr, GP, qv, TT, FF, DD, nullptr);

    // ---- gate (approx) + exact borderline fixup + scan ----
    gate2<<<TT / 256, blk, 0, stream>>>(SX, spb, GP, WG, MI, FLAGS, CNT);
    fixh<<<dim3(FF / 256, 4, CAP / 32), blk, 0, stream>>>(x, ew1, FLAGS, CNT, Hpart);
    fixres2<<<CAP / 4, blk, 0, stream>>>(SX, spb, Hpart, qv, FLAGS, CNT, WG, MI);
    scan_kernel<<<1, blk, 0, stream>>>(MI, cu, ECS, META);

    // ---- encoder GEMM2: ENCb = bf16(Hb @ ew2 + Xb) ----
    mgemm8<3, true, false, false, false><<<dim3(DD / 256, TT / 256), blk8, 131072, stream>>>(
        Hb, ew2T, nullptr, Xb, ENCb, nullptr, nullptr, nullptr, TT, DD, FF, nullptr);

    // ---- pack kept rows (bf16) ----
    pack_kernel<<<TT / 4, blk, 0, stream>>>(ENCb, WG, MI, ECS, cu, META, pem, Pb);

    // ---- backbone (rowlim) ----
    mgemm8<1, true, false, true, false><<<dim3(FF / 256, TT / 256), blk8, 131072, stream>>>(
        Pb, bw1T, nullptr, nullptr, Hb, nullptr, nullptr, nullptr, TT, FF, DD, META);
    mgemm8<3, true, false, true, false><<<dim3(DD / 256, TT / 256), blk8, 131072, stream>>>(
        Hb, bw2T, nullptr, Pb, BBb, nullptr, nullptr, nullptr, TT, DD, FF, META);

    // ---- scatter-combine (bf16 row select) ----
    combine_kernel<<<TT / 4, blk, 0, stream>>>(ENCb, BBb, MI, ECS, Cb);

    // ---- decoder ----
    mgemm8<1, true, false, false, false><<<dim3(FF / 256, TT / 256), blk8, 131072, stream>>>(
        Cb, dw1T, nullptr, nullptr, Hb, nullptr, nullptr, nullptr, TT, FF, DD, nullptr);
    mgemm8<3, true, false, false, false><<<dim3(DD / 256, TT / 256), blk8, 131072, stream>>>(
        Hb, dw2T, nullptr, Cb, DECb, nullptr, nullptr, nullptr, TT, DD, FF, nullptr);

    // ---- lm head ----
    mgemm8<0, false, true, false, false><<<dim3(VV / 256, TT / 256), blk8, 131072, stream>>>(
        DECb, lmhT, nullptr, nullptr, nullptr, out, nullptr, nullptr, TT, VV, DD, nullptr);
}